// Round 1
// baseline (3758.836 us; speedup 1.0000x reference)
//
#include <hip/hip_runtime.h>
#include <hip/hip_bf16.h>

namespace {

constexpr int B  = 128;
constexpr int T  = 200;
constexpr int D  = 256;
constexpr int H  = 4;
constexpr int NE = 4;
constexpr int NL = 2;
constexpr int HD = 64;
constexpr int BT = B * T;          // 25600 tokens
constexpr int TT = 20;             // token tile for mat-vec kernels
constexpr int NTILE = T / TT;      // 10
static_assert(T % TT == 0, "tile");

__device__ inline float wave_sum(float x) {
#pragma unroll
  for (int off = 32; off > 0; off >>= 1) x += __shfl_xor(x, off);
  return x;
}

// ---------------- embed: seqs = item_emb[log]*sqrt(D) + pos_emb[poss] ----------
__global__ void k_embed(const int* __restrict__ log_seqs,
                        const float* __restrict__ item_emb,
                        const float* __restrict__ pos_emb,
                        float* __restrict__ seqs) {
  int tok = blockIdx.x;                 // 0..BT-1
  int t = tok % T;
  int idx = log_seqs[tok];
  int pos = (idx != 0) ? (t + 1) : 0;
  int lane = threadIdx.x;               // 64 threads, 4 floats each
  float4 iv = ((const float4*)(item_emb + (size_t)idx * D))[lane];
  float4 pv = ((const float4*)(pos_emb + (size_t)pos * D))[lane];
  float4 r;
  r.x = iv.x * 16.0f + pv.x;
  r.y = iv.y * 16.0f + pv.y;
  r.z = iv.z * 16.0f + pv.z;
  r.w = iv.w * 16.0f + pv.w;
  ((float4*)(seqs + (size_t)tok * D))[lane] = r;
}

// ---------------- layernorm: one wave per row (D=256, 4 floats/lane) ----------
__global__ __launch_bounds__(256) void k_ln(const float* __restrict__ in,
                                            float* __restrict__ out,
                                            const float* __restrict__ sc,
                                            const float* __restrict__ bi) {
  int row = blockIdx.x * 4 + (threadIdx.x >> 6);
  int lane = threadIdx.x & 63;
  float4 x = ((const float4*)(in + (size_t)row * D))[lane];
  float mean = wave_sum(x.x + x.y + x.z + x.w) * (1.0f / D);
  float4 c;
  c.x = x.x - mean; c.y = x.y - mean; c.z = x.z - mean; c.w = x.w - mean;
  float var = wave_sum(c.x * c.x + c.y * c.y + c.z * c.z + c.w * c.w) * (1.0f / D);
  float inv = rsqrtf(var + 1e-8f);
  float4 sv = ((const float4*)sc)[lane];
  float4 bv = ((const float4*)bi)[lane];
  float4 r;
  r.x = c.x * inv * sv.x + bv.x;
  r.y = c.y * inv * sv.y + bv.y;
  r.z = c.z * inv * sv.z + bv.z;
  r.w = c.w * inv * sv.w + bv.w;
  ((float4*)(out + (size_t)row * D))[lane] = r;
}

// ---------------- fused QKV mat-vec, routed expert only ----------------------
// q[f] = dot(qn, wq[f]) ; k[f] = dot(seqs, wk[f]) ; v[f] = dot(seqs, wv[f])
__global__ __launch_bounds__(256) void k_qkv(const float* __restrict__ qn,
                                             const float* __restrict__ seqs,
                                             const float* __restrict__ w,     // [NE][3D][D]
                                             const float* __restrict__ bias,  // [NE][3D]
                                             const int* __restrict__ expert_ids,
                                             float* __restrict__ q,
                                             float* __restrict__ k,
                                             float* __restrict__ v) {
  int b = blockIdx.x / NTILE;
  int t0 = (blockIdx.x % NTILE) * TT;
  int e = expert_ids[b];
  const float* W = w + (size_t)e * 3 * D * D;
  __shared__ __align__(16) float Xq[TT][D];
  __shared__ __align__(16) float Xs[TT][D];
  for (int i = threadIdx.x; i < TT * D; i += 256) {
    int tt = i >> 8, d = i & 255;
    size_t row = (size_t)(b * T + t0 + tt) * D + d;
    Xq[tt][d] = qn[row];
    Xs[tt][d] = seqs[row];
  }
  __syncthreads();

  int f0 = threadIdx.x;  // q column; k = f0+256; v = f0+512
  float acc0[TT], acc1[TT], acc2[TT];
#pragma unroll
  for (int t = 0; t < TT; t++) { acc0[t] = 0.f; acc1[t] = 0.f; acc2[t] = 0.f; }
  const float4* W0 = (const float4*)(W + (size_t)f0 * D);
  const float4* W1 = (const float4*)(W + (size_t)(f0 + 256) * D);
  const float4* W2 = (const float4*)(W + (size_t)(f0 + 512) * D);
  for (int c = 0; c < D / 4; c++) {
    float4 w0 = W0[c], w1 = W1[c], w2 = W2[c];
#pragma unroll
    for (int t = 0; t < TT; t++) {
      float4 xq = ((const float4*)Xq[t])[c];
      float4 xs = ((const float4*)Xs[t])[c];
      acc0[t] += w0.x * xq.x + w0.y * xq.y + w0.z * xq.z + w0.w * xq.w;
      acc1[t] += w1.x * xs.x + w1.y * xs.y + w1.z * xs.z + w1.w * xs.w;
      acc2[t] += w2.x * xs.x + w2.y * xs.y + w2.z * xs.z + w2.w * xs.w;
    }
  }
  float b0 = bias[e * 3 * D + f0];
  float b1 = bias[e * 3 * D + 256 + f0];
  float b2 = bias[e * 3 * D + 512 + f0];
#pragma unroll
  for (int t = 0; t < TT; t++) {
    size_t row = (size_t)(b * T + t0 + t) * D + f0;
    q[row] = acc0[t] + b0;
    k[row] = acc1[t] + b1;
    v[row] = acc2[t] + b2;
  }
}

// ---------------- attention: one block per (b,h); K,V staged bf16 in LDS -----
__global__ __launch_bounds__(256) void k_attn(const float* __restrict__ q,
                                              const float* __restrict__ k,
                                              const float* __restrict__ v,
                                              float* __restrict__ o) {
  int bh = blockIdx.x;
  int b = bh >> 2, h = bh & 3;
  __shared__ __hip_bfloat16 Kl[T][HD];
  __shared__ __hip_bfloat16 Vl[T][HD];
  const size_t base = (size_t)b * T * D + h * HD;
  for (int i = threadIdx.x; i < T * HD; i += 256) {
    int t = i >> 6, d = i & 63;
    Kl[t][d] = __float2bfloat16(k[base + (size_t)t * D + d]);
    Vl[t][d] = __float2bfloat16(v[base + (size_t)t * D + d]);
  }
  __syncthreads();

  int wave = threadIdx.x >> 6, lane = threadIdx.x & 63;
  for (int row = wave; row < T; row += 4) {
    float qv = q[base + (size_t)row * D + lane] * 0.125f;  // 1/sqrt(64)
    float m = -3e38f, l = 0.f, acc = 0.f;
    for (int kk = 0; kk <= row; kk++) {
      float s = qv * __bfloat162float(Kl[kk][lane]);
#pragma unroll
      for (int off = 32; off > 0; off >>= 1) s += __shfl_xor(s, off);
      float mn = fmaxf(m, s);
      float corr = __expf(m - mn);
      float p = __expf(s - mn);
      l = l * corr + p;
      acc = acc * corr + p * __bfloat162float(Vl[kk][lane]);
      m = mn;
    }
    o[base + (size_t)row * D + lane] = acc / l;
  }
}

// ---------------- generic 256->256 mat-vec -----------------------------------
// MODE 0: out = relu(x@W^T + b)            (FFN1)
// MODE 1: out += x@W^T + b                  (FFN2 residual)
// MODE 2: out = add + x@W^T + b[expert]     (out-proj, routed expert, +qn resid)
template <int MODE>
__global__ __launch_bounds__(256) void k_matvec(const float* __restrict__ x,
                                                const float* __restrict__ w,
                                                const float* __restrict__ bias,
                                                const float* __restrict__ add,
                                                float* __restrict__ out,
                                                const int* __restrict__ expert_ids) {
  int b = blockIdx.x / NTILE;
  int t0 = (blockIdx.x % NTILE) * TT;
  const float* W = w;
  const float* bi = bias;
  if (MODE == 2) {
    int e = expert_ids[b];
    W += (size_t)e * D * D;
    bi += (size_t)e * D;
  }
  __shared__ __align__(16) float X[TT][D];
  for (int i = threadIdx.x; i < TT * D; i += 256) {
    int tt = i >> 8, d = i & 255;
    X[tt][d] = x[(size_t)(b * T + t0 + tt) * D + d];
  }
  __syncthreads();

  int f = threadIdx.x;
  float acc[TT];
#pragma unroll
  for (int t = 0; t < TT; t++) acc[t] = 0.f;
  const float4* Wf = (const float4*)(W + (size_t)f * D);
  for (int c = 0; c < D / 4; c++) {
    float4 wv = Wf[c];
#pragma unroll
    for (int t = 0; t < TT; t++) {
      float4 xv = ((const float4*)X[t])[c];
      acc[t] += wv.x * xv.x + wv.y * xv.y + wv.z * xv.z + wv.w * xv.w;
    }
  }
  float bb = bi[f];
#pragma unroll
  for (int t = 0; t < TT; t++) {
    size_t idx = (size_t)(b * T + t0 + t) * D + f;
    float r = acc[t] + bb;
    if (MODE == 0) out[idx] = fmaxf(r, 0.f);
    else if (MODE == 1) out[idx] += r;
    else out[idx] = add[idx] + r;
  }
}

// ---------------- final LN + pos/neg logits ----------------------------------
__global__ __launch_bounds__(256) void k_final(const float* __restrict__ seqs,
                                               const float* __restrict__ sc,
                                               const float* __restrict__ bi,
                                               const int* __restrict__ pos_seqs,
                                               const int* __restrict__ neg_seqs,
                                               const float* __restrict__ item_emb,
                                               float* __restrict__ out) {
  int tok = blockIdx.x * 4 + (threadIdx.x >> 6);
  int lane = threadIdx.x & 63;
  float4 x = ((const float4*)(seqs + (size_t)tok * D))[lane];
  float mean = wave_sum(x.x + x.y + x.z + x.w) * (1.0f / D);
  float4 c;
  c.x = x.x - mean; c.y = x.y - mean; c.z = x.z - mean; c.w = x.w - mean;
  float var = wave_sum(c.x * c.x + c.y * c.y + c.z * c.z + c.w * c.w) * (1.0f / D);
  float inv = rsqrtf(var + 1e-8f);
  float4 sv = ((const float4*)sc)[lane];
  float4 bv = ((const float4*)bi)[lane];
  float4 f;
  f.x = c.x * inv * sv.x + bv.x;
  f.y = c.y * inv * sv.y + bv.y;
  f.z = c.z * inv * sv.z + bv.z;
  f.w = c.w * inv * sv.w + bv.w;
  int ip = pos_seqs[tok];
  int in_ = neg_seqs[tok];
  float4 pe = ((const float4*)(item_emb + (size_t)ip * D))[lane];
  float4 ne = ((const float4*)(item_emb + (size_t)in_ * D))[lane];
  float dp = wave_sum(f.x * pe.x + f.y * pe.y + f.z * pe.z + f.w * pe.w);
  float dn = wave_sum(f.x * ne.x + f.y * ne.y + f.z * ne.z + f.w * ne.w);
  if (lane == 0) {
    out[tok] = dp;
    out[BT + tok] = dn;
  }
}

}  // namespace

extern "C" void kernel_launch(void* const* d_in, const int* in_sizes, int n_in,
                              void* d_out, int out_size, void* d_ws, size_t ws_size,
                              hipStream_t stream) {
  const int*   log_seqs   = (const int*)d_in[0];
  const int*   pos_seqs   = (const int*)d_in[1];
  const int*   neg_seqs   = (const int*)d_in[2];
  const int*   expert_ids = (const int*)d_in[3];
  const float* item_emb   = (const float*)d_in[4];
  const float* pos_emb    = (const float*)d_in[5];
  const float* attn_ln_s  = (const float*)d_in[6];
  const float* attn_ln_b  = (const float*)d_in[7];
  const float* in_w       = (const float*)d_in[8];
  const float* in_b       = (const float*)d_in[9];
  const float* out_w      = (const float*)d_in[10];
  const float* out_b      = (const float*)d_in[11];
  const float* fwd_ln_s   = (const float*)d_in[12];
  const float* fwd_ln_b   = (const float*)d_in[13];
  const float* ffn_w1     = (const float*)d_in[14];
  const float* ffn_b1     = (const float*)d_in[15];
  const float* ffn_w2     = (const float*)d_in[16];
  const float* ffn_b2     = (const float*)d_in[17];
  const float* last_ln_s  = (const float*)d_in[18];
  const float* last_ln_b  = (const float*)d_in[19];
  float* out = (float*)d_out;

  const size_t N = (size_t)BT * D;          // 6.55M floats per buffer
  float* seqs = (float*)d_ws;
  float* qn   = seqs + N;
  float* q    = qn + N;
  float* kbuf = q + N;
  float* vbuf = kbuf + N;
  float* obuf = kbuf;   // alias: o overwrites k (K fully LDS-staged before writes)
  float* hbuf = q;      // alias: FFN hidden reuses q

  k_embed<<<BT, 64, 0, stream>>>(log_seqs, item_emb, pos_emb, seqs);

  for (int l = 0; l < NL; l++) {
    k_ln<<<BT / 4, 256, 0, stream>>>(seqs, qn, attn_ln_s + (size_t)l * D,
                                     attn_ln_b + (size_t)l * D);
    k_qkv<<<B * NTILE, 256, 0, stream>>>(
        qn, seqs, in_w + (size_t)l * NE * 3 * D * D, in_b + (size_t)l * NE * 3 * D,
        expert_ids, q, kbuf, vbuf);
    k_attn<<<B * H, 256, 0, stream>>>(q, kbuf, vbuf, obuf);
    k_matvec<2><<<B * NTILE, 256, 0, stream>>>(
        obuf, out_w + (size_t)l * NE * D * D, out_b + (size_t)l * NE * D, qn, seqs,
        expert_ids);
    k_ln<<<BT / 4, 256, 0, stream>>>(seqs, seqs, fwd_ln_s + (size_t)l * D,
                                     fwd_ln_b + (size_t)l * D);
    k_matvec<0><<<B * NTILE, 256, 0, stream>>>(
        seqs, ffn_w1 + (size_t)l * D * D, ffn_b1 + (size_t)l * D, nullptr, hbuf,
        expert_ids);
    k_matvec<1><<<B * NTILE, 256, 0, stream>>>(
        hbuf, ffn_w2 + (size_t)l * D * D, ffn_b2 + (size_t)l * D, nullptr, seqs,
        expert_ids);
  }

  k_final<<<BT / 4, 256, 0, stream>>>(seqs, last_ln_s, last_ln_b, pos_seqs,
                                      neg_seqs, item_emb, out);
}

// Round 2
// 2059.905 us; speedup vs baseline: 1.8248x; 1.8248x over previous
//
#include <hip/hip_runtime.h>
#include <hip/hip_bf16.h>

namespace {

constexpr int B  = 128;
constexpr int T  = 200;
constexpr int D  = 256;
constexpr int H  = 4;
constexpr int NE = 4;
constexpr int NL = 2;
constexpr int HD = 64;
constexpr int BT = B * T;          // 25600 tokens
constexpr int TT = 20;             // token tile for matvec kernels
constexpr int NTILE = T / TT;      // 10
constexpr int TTQ = 10;            // token tile for qkv (3x accs -> keep regs)
constexpr int NTILEQ = T / TTQ;    // 20
static_assert(T % TT == 0 && T % TTQ == 0, "tile");

__device__ inline float wave_sum(float x) {
#pragma unroll
  for (int off = 32; off > 0; off >>= 1) x += __shfl_xor(x, off);
  return x;
}
__device__ inline float wave_max(float x) {
#pragma unroll
  for (int off = 32; off > 0; off >>= 1) x = fmaxf(x, __shfl_xor(x, off));
  return x;
}
__device__ inline unsigned int f2bf(float x) {  // round-to-nearest-even bf16
  unsigned int u = __float_as_uint(x);
  return (u + 0x7fffu + ((u >> 16) & 1u)) >> 16;
}

// ---------------- embed: seqs = item_emb[log]*sqrt(D) + pos_emb[poss] ----------
__global__ void k_embed(const int* __restrict__ log_seqs,
                        const float* __restrict__ item_emb,
                        const float* __restrict__ pos_emb,
                        float* __restrict__ seqs) {
  int tok = blockIdx.x;
  int t = tok % T;
  int idx = log_seqs[tok];
  int pos = (idx != 0) ? (t + 1) : 0;
  int lane = threadIdx.x;
  float4 iv = ((const float4*)(item_emb + (size_t)idx * D))[lane];
  float4 pv = ((const float4*)(pos_emb + (size_t)pos * D))[lane];
  float4 r;
  r.x = iv.x * 16.0f + pv.x;
  r.y = iv.y * 16.0f + pv.y;
  r.z = iv.z * 16.0f + pv.z;
  r.w = iv.w * 16.0f + pv.w;
  ((float4*)(seqs + (size_t)tok * D))[lane] = r;
}

// ---------------- layernorm: one wave per row ----------------
__global__ __launch_bounds__(256) void k_ln(const float* __restrict__ in,
                                            float* __restrict__ out,
                                            const float* __restrict__ sc,
                                            const float* __restrict__ bi) {
  int row = blockIdx.x * 4 + (threadIdx.x >> 6);
  int lane = threadIdx.x & 63;
  float4 x = ((const float4*)(in + (size_t)row * D))[lane];
  float mean = wave_sum(x.x + x.y + x.z + x.w) * (1.0f / D);
  float4 c;
  c.x = x.x - mean; c.y = x.y - mean; c.z = x.z - mean; c.w = x.w - mean;
  float var = wave_sum(c.x * c.x + c.y * c.y + c.z * c.z + c.w * c.w) * (1.0f / D);
  float inv = rsqrtf(var + 1e-8f);
  float4 sv = ((const float4*)sc)[lane];
  float4 bv = ((const float4*)bi)[lane];
  float4 r;
  r.x = c.x * inv * sv.x + bv.x;
  r.y = c.y * inv * sv.y + bv.y;
  r.z = c.z * inv * sv.z + bv.z;
  r.w = c.w * inv * sv.w + bv.w;
  ((float4*)(out + (size_t)row * D))[lane] = r;
}

// ---------------- fused QKV mat-vec, routed expert only ----------------------
__global__ __launch_bounds__(256) void k_qkv(const float* __restrict__ qn,
                                             const float* __restrict__ seqs,
                                             const float* __restrict__ w,     // [NE][3D][D]
                                             const float* __restrict__ bias,  // [NE][3D]
                                             const int* __restrict__ expert_ids,
                                             float* __restrict__ q,
                                             float* __restrict__ k,
                                             float* __restrict__ v) {
  int b = blockIdx.x / NTILEQ;
  int t0 = (blockIdx.x % NTILEQ) * TTQ;
  int e = expert_ids[b];
  const float* W = w + (size_t)e * 3 * D * D;
  __shared__ __align__(16) float Xq[TTQ][D];
  __shared__ __align__(16) float Xs[TTQ][D];
  for (int i = threadIdx.x; i < TTQ * D; i += 256) {
    int tt = i >> 8, d = i & 255;
    size_t row = (size_t)(b * T + t0 + tt) * D + d;
    Xq[tt][d] = qn[row];
    Xs[tt][d] = seqs[row];
  }
  __syncthreads();

  int f0 = threadIdx.x;
  float acc0[TTQ], acc1[TTQ], acc2[TTQ];
#pragma unroll
  for (int t = 0; t < TTQ; t++) { acc0[t] = 0.f; acc1[t] = 0.f; acc2[t] = 0.f; }
  const float4* W0 = (const float4*)(W + (size_t)f0 * D);
  const float4* W1 = (const float4*)(W + (size_t)(f0 + 256) * D);
  const float4* W2 = (const float4*)(W + (size_t)(f0 + 512) * D);
  for (int c = 0; c < D / 4; c++) {
    float4 w0 = W0[c], w1 = W1[c], w2 = W2[c];
#pragma unroll
    for (int t = 0; t < TTQ; t++) {
      float4 xq = ((const float4*)Xq[t])[c];
      float4 xs = ((const float4*)Xs[t])[c];
      acc0[t] += w0.x * xq.x + w0.y * xq.y + w0.z * xq.z + w0.w * xq.w;
      acc1[t] += w1.x * xs.x + w1.y * xs.y + w1.z * xs.z + w1.w * xs.w;
      acc2[t] += w2.x * xs.x + w2.y * xs.y + w2.z * xs.z + w2.w * xs.w;
    }
  }
  float b0 = bias[e * 3 * D + f0];
  float b1 = bias[e * 3 * D + 256 + f0];
  float b2 = bias[e * 3 * D + 512 + f0];
#pragma unroll
  for (int t = 0; t < TTQ; t++) {
    size_t row = (size_t)(b * T + t0 + t) * D + f0;
    q[row] = acc0[t] + b0;
    k[row] = acc1[t] + b1;
    v[row] = acc2[t] + b2;
  }
}

// ---------------- attention: wave-parallel two-phase online softmax ----------
// one block per (b,h); 4 waves, rows strided by 4.
// phase 1: lane = key, dot(q,K[key]) from transposed packed-bf16 K tile
// phase 2: lane = d,   acc += p[key]*V[key][d] with online rescale
constexpr int KTP = T + 1;   // padded stride (201 words): 201%32=9, gcd(9,32)=1
__global__ __launch_bounds__(256) void k_attn(const float* __restrict__ q,
                                              const float* __restrict__ k,
                                              const float* __restrict__ v,
                                              float* __restrict__ o) {
  int bh = blockIdx.x;
  int b = bh >> 2, h = bh & 3;
  __shared__ unsigned int Kt[HD / 2][KTP];     // packed bf16x2, transposed
  __shared__ float Vl[T + 4][HD];              // fp32, +4 zero pad rows
  __shared__ float Ps[4][64];
  __shared__ float Qs[4][HD];
  const size_t base = (size_t)b * T * D + h * HD;
  int tid = threadIdx.x, wave = tid >> 6, lane = tid & 63;

  // stage K: 8 rows/pass, 32 threads per row (float2 each), write transposed
  for (int kk0 = 0; kk0 < T; kk0 += 8) {
    int kk = kk0 + (tid >> 5);
    int d2 = tid & 31;
    float2 kv = ((const float2*)(k + base + (size_t)kk * D))[d2];
    Kt[d2][kk] = f2bf(kv.x) | (f2bf(kv.y) << 16);
  }
  // stage V (coalesced, conflict-free)
  for (int i = tid; i < T * HD; i += 256) {
    int kk = i >> 6, d = i & 63;
    Vl[kk][d] = v[base + (size_t)kk * D + d];
  }
  Vl[T + (tid >> 6)][tid & 63] = 0.f;          // zero the pad rows
  __syncthreads();

  for (int row = wave; row < T; row += 4) {
    Qs[wave][lane] = q[base + (size_t)row * D + lane] * 0.125f;  // 1/sqrt(HD)
    float m = -3e38f, l = 0.f, acc = 0.f;
    int nc = (row >> 6) + 1;
    for (int c = 0; c < nc; c++) {
      int kk = (c << 6) + lane;
      bool act = (kk <= row);
      float s = -1e30f;
      if (act) {
        float sum = 0.f;
        const float2* qp = (const float2*)Qs[wave];
#pragma unroll
        for (int d2 = 0; d2 < HD / 2; d2++) {
          unsigned int pk = Kt[d2][kk];
          float2 qv = qp[d2];                              // LDS broadcast
          float lo = __uint_as_float(pk << 16);
          float hi = __uint_as_float(pk & 0xffff0000u);
          sum += qv.x * lo + qv.y * hi;
        }
        s = sum;
      }
      float mnew = fmaxf(m, wave_max(s));
      float p = act ? __expf(s - mnew) : 0.f;
      float psum = wave_sum(p);
      float corr = __expf(m - mnew);
      l = l * corr + psum;
      m = mnew;
      Ps[wave][lane] = p;
      // phase 2: this lane owns output dim `lane`
      int kmax4 = ((row - (c << 6)) + 4) & ~3;   // multiple of 4, pad p==0
      float a = 0.f;
      const float4* pp = (const float4*)Ps[wave];
      for (int j4 = 0; j4 < (kmax4 >> 2); j4++) {
        float4 pv = pp[j4];                                // LDS broadcast
        int kb = (c << 6) + (j4 << 2);
        a += pv.x * Vl[kb + 0][lane];
        a += pv.y * Vl[kb + 1][lane];
        a += pv.z * Vl[kb + 2][lane];
        a += pv.w * Vl[kb + 3][lane];
      }
      acc = acc * corr + a;
    }
    o[base + (size_t)row * D + lane] = acc / l;
  }
}

// ---------------- generic 256->256 mat-vec -----------------------------------
template <int MODE>
__global__ __launch_bounds__(256) void k_matvec(const float* __restrict__ x,
                                                const float* __restrict__ w,
                                                const float* __restrict__ bias,
                                                const float* __restrict__ add,
                                                float* __restrict__ out,
                                                const int* __restrict__ expert_ids) {
  int b = blockIdx.x / NTILE;
  int t0 = (blockIdx.x % NTILE) * TT;
  const float* W = w;
  const float* bi = bias;
  if (MODE == 2) {
    int e = expert_ids[b];
    W += (size_t)e * D * D;
    bi += (size_t)e * D;
  }
  __shared__ __align__(16) float X[TT][D];
  for (int i = threadIdx.x; i < TT * D; i += 256) {
    int tt = i >> 8, d = i & 255;
    X[tt][d] = x[(size_t)(b * T + t0 + tt) * D + d];
  }
  __syncthreads();

  int f = threadIdx.x;
  float acc[TT];
#pragma unroll
  for (int t = 0; t < TT; t++) acc[t] = 0.f;
  const float4* Wf = (const float4*)(W + (size_t)f * D);
  for (int c = 0; c < D / 4; c++) {
    float4 wv = Wf[c];
#pragma unroll
    for (int t = 0; t < TT; t++) {
      float4 xv = ((const float4*)X[t])[c];
      acc[t] += wv.x * xv.x + wv.y * xv.y + wv.z * xv.z + wv.w * xv.w;
    }
  }
  float bb = bi[f];
#pragma unroll
  for (int t = 0; t < TT; t++) {
    size_t idx = (size_t)(b * T + t0 + t) * D + f;
    float r = acc[t] + bb;
    if (MODE == 0) out[idx] = fmaxf(r, 0.f);
    else if (MODE == 1) out[idx] += r;
    else out[idx] = add[idx] + r;
  }
}

// ---------------- final LN + pos/neg logits ----------------------------------
__global__ __launch_bounds__(256) void k_final(const float* __restrict__ seqs,
                                               const float* __restrict__ sc,
                                               const float* __restrict__ bi,
                                               const int* __restrict__ pos_seqs,
                                               const int* __restrict__ neg_seqs,
                                               const float* __restrict__ item_emb,
                                               float* __restrict__ out) {
  int tok = blockIdx.x * 4 + (threadIdx.x >> 6);
  int lane = threadIdx.x & 63;
  float4 x = ((const float4*)(seqs + (size_t)tok * D))[lane];
  float mean = wave_sum(x.x + x.y + x.z + x.w) * (1.0f / D);
  float4 c;
  c.x = x.x - mean; c.y = x.y - mean; c.z = x.z - mean; c.w = x.w - mean;
  float var = wave_sum(c.x * c.x + c.y * c.y + c.z * c.z + c.w * c.w) * (1.0f / D);
  float inv = rsqrtf(var + 1e-8f);
  float4 sv = ((const float4*)sc)[lane];
  float4 bv = ((const float4*)bi)[lane];
  float4 f;
  f.x = c.x * inv * sv.x + bv.x;
  f.y = c.y * inv * sv.y + bv.y;
  f.z = c.z * inv * sv.z + bv.z;
  f.w = c.w * inv * sv.w + bv.w;
  int ip = pos_seqs[tok];
  int in_ = neg_seqs[tok];
  float4 pe = ((const float4*)(item_emb + (size_t)ip * D))[lane];
  float4 ne = ((const float4*)(item_emb + (size_t)in_ * D))[lane];
  float dp = wave_sum(f.x * pe.x + f.y * pe.y + f.z * pe.z + f.w * pe.w);
  float dn = wave_sum(f.x * ne.x + f.y * ne.y + f.z * ne.z + f.w * ne.w);
  if (lane == 0) {
    out[tok] = dp;
    out[BT + tok] = dn;
  }
}

}  // namespace

extern "C" void kernel_launch(void* const* d_in, const int* in_sizes, int n_in,
                              void* d_out, int out_size, void* d_ws, size_t ws_size,
                              hipStream_t stream) {
  const int*   log_seqs   = (const int*)d_in[0];
  const int*   pos_seqs   = (const int*)d_in[1];
  const int*   neg_seqs   = (const int*)d_in[2];
  const int*   expert_ids = (const int*)d_in[3];
  const float* item_emb   = (const float*)d_in[4];
  const float* pos_emb    = (const float*)d_in[5];
  const float* attn_ln_s  = (const float*)d_in[6];
  const float* attn_ln_b  = (const float*)d_in[7];
  const float* in_w       = (const float*)d_in[8];
  const float* in_b       = (const float*)d_in[9];
  const float* out_w      = (const float*)d_in[10];
  const float* out_b      = (const float*)d_in[11];
  const float* fwd_ln_s   = (const float*)d_in[12];
  const float* fwd_ln_b   = (const float*)d_in[13];
  const float* ffn_w1     = (const float*)d_in[14];
  const float* ffn_b1     = (const float*)d_in[15];
  const float* ffn_w2     = (const float*)d_in[16];
  const float* ffn_b2     = (const float*)d_in[17];
  const float* last_ln_s  = (const float*)d_in[18];
  const float* last_ln_b  = (const float*)d_in[19];
  float* out = (float*)d_out;

  const size_t N = (size_t)BT * D;
  float* seqs = (float*)d_ws;
  float* qn   = seqs + N;
  float* q    = qn + N;
  float* kbuf = q + N;
  float* vbuf = kbuf + N;
  float* obuf = kbuf;   // alias: block (b,h) reads/writes only its own h-column slice
  float* hbuf = q;      // alias: FFN hidden reuses q

  k_embed<<<BT, 64, 0, stream>>>(log_seqs, item_emb, pos_emb, seqs);

  for (int l = 0; l < NL; l++) {
    k_ln<<<BT / 4, 256, 0, stream>>>(seqs, qn, attn_ln_s + (size_t)l * D,
                                     attn_ln_b + (size_t)l * D);
    k_qkv<<<B * NTILEQ, 256, 0, stream>>>(
        qn, seqs, in_w + (size_t)l * NE * 3 * D * D, in_b + (size_t)l * NE * 3 * D,
        expert_ids, q, kbuf, vbuf);
    k_attn<<<B * H, 256, 0, stream>>>(q, kbuf, vbuf, obuf);
    k_matvec<2><<<B * NTILE, 256, 0, stream>>>(
        obuf, out_w + (size_t)l * NE * D * D, out_b + (size_t)l * NE * D, qn, seqs,
        expert_ids);
    k_ln<<<BT / 4, 256, 0, stream>>>(seqs, seqs, fwd_ln_s + (size_t)l * D,
                                     fwd_ln_b + (size_t)l * D);
    k_matvec<0><<<B * NTILE, 256, 0, stream>>>(
        seqs, ffn_w1 + (size_t)l * D * D, ffn_b1 + (size_t)l * D, nullptr, hbuf,
        expert_ids);
    k_matvec<1><<<B * NTILE, 256, 0, stream>>>(
        hbuf, ffn_w2 + (size_t)l * D * D, ffn_b2 + (size_t)l * D, nullptr, seqs,
        expert_ids);
  }

  k_final<<<BT / 4, 256, 0, stream>>>(seqs, last_ln_s, last_ln_b, pos_seqs,
                                      neg_seqs, item_emb, out);
}

// Round 3
// 922.442 us; speedup vs baseline: 4.0749x; 2.2331x over previous
//
#include <hip/hip_runtime.h>
#include <hip/hip_bf16.h>

namespace {

constexpr int B  = 128;
constexpr int T  = 200;
constexpr int D  = 256;
constexpr int H  = 4;
constexpr int NE = 4;
constexpr int NL = 2;
constexpr int HD = 64;
constexpr int BT = B * T;

// ---- MFMA GEMM tiling ----
constexpr int BM = 64;
constexpr int BN = 128;
constexpr int BK = 32;
constexpr int MT = (T + BM - 1) / BM;   // 4 M-tiles (last has 8 valid rows)
constexpr int XS = BK + 8;              // padded LDS stride (ushorts) -> 2-way max

typedef __bf16 bf16x8 __attribute__((ext_vector_type(8)));
typedef float f32x4 __attribute__((ext_vector_type(4)));
typedef unsigned short ushort8v __attribute__((ext_vector_type(8)));

__device__ inline float wave_sum(float x) {
#pragma unroll
  for (int off = 32; off > 0; off >>= 1) x += __shfl_xor(x, off);
  return x;
}
__device__ inline float wave_max(float x) {
#pragma unroll
  for (int off = 32; off > 0; off >>= 1) x = fmaxf(x, __shfl_xor(x, off));
  return x;
}
__device__ inline unsigned int f2bf(float x) {  // RNE bf16 (as uint)
  unsigned int u = __float_as_uint(x);
  return (u + 0x7fffu + ((u >> 16) & 1u)) >> 16;
}
__device__ inline unsigned short f2bfs(float x) {
  return (unsigned short)f2bf(x);
}

// stage ROWS x BK fp32 tile -> bf16 LDS [ROWS][XS]; rows >= valid zero-filled
template <int ROWS>
__device__ inline void stage_tile(const float* __restrict__ src, int ld,
                                  int valid, int k0,
                                  unsigned short (*dst)[XS], int tid) {
#pragma unroll
  for (int p = 0; p < ROWS / 32; p++) {
    int slot = p * 256 + tid;
    int r = slot >> 3, c4 = (slot & 7) << 2;
    float4 v = make_float4(0.f, 0.f, 0.f, 0.f);
    if (r < valid) v = *(const float4*)(src + (size_t)r * ld + k0 + c4);
    ushort4 s;
    s.x = f2bfs(v.x); s.y = f2bfs(v.y); s.z = f2bfs(v.z); s.w = f2bfs(v.w);
    *(ushort4*)&dst[r][c4] = s;
  }
}

// ---------------- embed ----------------
__global__ void k_embed(const int* __restrict__ log_seqs,
                        const float* __restrict__ item_emb,
                        const float* __restrict__ pos_emb,
                        float* __restrict__ seqs) {
  int tok = blockIdx.x;
  int t = tok % T;
  int idx = log_seqs[tok];
  int pos = (idx != 0) ? (t + 1) : 0;
  int lane = threadIdx.x;
  float4 iv = ((const float4*)(item_emb + (size_t)idx * D))[lane];
  float4 pv = ((const float4*)(pos_emb + (size_t)pos * D))[lane];
  float4 r;
  r.x = iv.x * 16.0f + pv.x;
  r.y = iv.y * 16.0f + pv.y;
  r.z = iv.z * 16.0f + pv.z;
  r.w = iv.w * 16.0f + pv.w;
  ((float4*)(seqs + (size_t)tok * D))[lane] = r;
}

// ---------------- layernorm ----------------
__global__ __launch_bounds__(256) void k_ln(const float* __restrict__ in,
                                            float* __restrict__ out,
                                            const float* __restrict__ sc,
                                            const float* __restrict__ bi) {
  int row = blockIdx.x * 4 + (threadIdx.x >> 6);
  int lane = threadIdx.x & 63;
  float4 x = ((const float4*)(in + (size_t)row * D))[lane];
  float mean = wave_sum(x.x + x.y + x.z + x.w) * (1.0f / D);
  float4 c;
  c.x = x.x - mean; c.y = x.y - mean; c.z = x.z - mean; c.w = x.w - mean;
  float var = wave_sum(c.x * c.x + c.y * c.y + c.z * c.z + c.w * c.w) * (1.0f / D);
  float inv = rsqrtf(var + 1e-8f);
  float4 sv = ((const float4*)sc)[lane];
  float4 bv = ((const float4*)bi)[lane];
  float4 r;
  r.x = c.x * inv * sv.x + bv.x;
  r.y = c.y * inv * sv.y + bv.y;
  r.z = c.z * inv * sv.z + bv.z;
  r.w = c.w * inv * sv.w + bv.w;
  ((float4*)(out + (size_t)row * D))[lane] = r;
}

// ---------------- QKV GEMM (bf16 MFMA), routed expert ------------------------
// grid: B * MT * 6 ; N-tiles 0-1 -> q (X=qn), 2-3 -> k, 4-5 -> v (X=seqs)
__global__ __launch_bounds__(256) void k_gemm_qkv(
    const float* __restrict__ qn, const float* __restrict__ seqs,
    const float* __restrict__ w, const float* __restrict__ bias,
    const int* __restrict__ expert_ids,
    float* __restrict__ q, float* __restrict__ k, float* __restrict__ v) {
  int bid = blockIdx.x;
  int nt = bid % 6;
  int mt = (bid / 6) % MT;
  int b  = bid / (6 * MT);
  int e = expert_ids[b];
  int m0 = mt * BM;
  int valid = min(BM, T - m0);
  const float* X = (nt < 2) ? qn : seqs;
  const float* Xb = X + (size_t)(b * T + m0) * D;
  const float* Wb = w + (size_t)e * 3 * D * D + (size_t)nt * BN * D;

  __shared__ __align__(16) unsigned short Xl[BM][XS];
  __shared__ __align__(16) unsigned short Wl[BN][XS];
  int tid = threadIdx.x, wv = tid >> 6, lane = tid & 63;
  int g = lane >> 4, lm = lane & 15;

  f32x4 acc[4][2];
#pragma unroll
  for (int mi = 0; mi < 4; mi++)
#pragma unroll
    for (int ni = 0; ni < 2; ni++) acc[mi][ni] = (f32x4){0.f, 0.f, 0.f, 0.f};

  for (int kt = 0; kt < D / BK; kt++) {
    stage_tile<BM>(Xb, D, valid, kt * BK, Xl, tid);
    stage_tile<BN>(Wb, D, BN, kt * BK, Wl, tid);
    __syncthreads();
    bf16x8 af[4], bf[2];
#pragma unroll
    for (int mi = 0; mi < 4; mi++)
      af[mi] = __builtin_bit_cast(bf16x8, *(const ushort8v*)&Xl[mi * 16 + lm][g * 8]);
#pragma unroll
    for (int ni = 0; ni < 2; ni++)
      bf[ni] = __builtin_bit_cast(bf16x8, *(const ushort8v*)&Wl[wv * 32 + ni * 16 + lm][g * 8]);
#pragma unroll
    for (int mi = 0; mi < 4; mi++)
#pragma unroll
      for (int ni = 0; ni < 2; ni++)
        acc[mi][ni] = __builtin_amdgcn_mfma_f32_16x16x32_bf16(af[mi], bf[ni],
                                                              acc[mi][ni], 0, 0, 0);
    __syncthreads();
  }

  float* outb = (nt < 2) ? q : (nt < 4 ? k : v);
  int lc0 = (nt & 1) * 128 + wv * 32;
  size_t rowbase = (size_t)(b * T + m0);
#pragma unroll
  for (int mi = 0; mi < 4; mi++) {
#pragma unroll
    for (int ni = 0; ni < 2; ni++) {
      int col = lc0 + ni * 16 + lm;
      float bb = bias[e * 3 * D + nt * 128 + wv * 32 + ni * 16 + lm];
#pragma unroll
      for (int r = 0; r < 4; r++) {
        int lr = mi * 16 + 4 * g + r;
        if (lr < valid)
          outb[(rowbase + lr) * D + col] = acc[mi][ni][r] + bb;
      }
    }
  }
}

// ---------------- generic 256x256 GEMM (bf16 MFMA) ---------------------------
// MODE 0: out = add + X@W_e^T + b_e   (out-proj, routed expert)
// MODE 1: out = relu(X@W^T + b)       (FFN1)
// MODE 2: out = out + X@W^T + b       (FFN2 residual)
template <int MODE>
__global__ __launch_bounds__(256) void k_gemm(
    const float* __restrict__ X, const float* __restrict__ w,
    const float* __restrict__ bias, const float* __restrict__ add,
    float* __restrict__ out, const int* __restrict__ expert_ids) {
  int bid = blockIdx.x;
  int nt = bid & 1;
  int mt = (bid >> 1) % MT;
  int b  = bid / (2 * MT);
  int m0 = mt * BM;
  int valid = min(BM, T - m0);
  const float* W = w;
  const float* bi = bias;
  if (MODE == 0) {
    int e = expert_ids[b];
    W += (size_t)e * D * D;
    bi += (size_t)e * D;
  }
  const float* Xb = X + (size_t)(b * T + m0) * D;
  const float* Wb = W + (size_t)nt * BN * D;

  __shared__ __align__(16) unsigned short Xl[BM][XS];
  __shared__ __align__(16) unsigned short Wl[BN][XS];
  int tid = threadIdx.x, wv = tid >> 6, lane = tid & 63;
  int g = lane >> 4, lm = lane & 15;

  f32x4 acc[4][2];
#pragma unroll
  for (int mi = 0; mi < 4; mi++)
#pragma unroll
    for (int ni = 0; ni < 2; ni++) acc[mi][ni] = (f32x4){0.f, 0.f, 0.f, 0.f};

  for (int kt = 0; kt < D / BK; kt++) {
    stage_tile<BM>(Xb, D, valid, kt * BK, Xl, tid);
    stage_tile<BN>(Wb, D, BN, kt * BK, Wl, tid);
    __syncthreads();
    bf16x8 af[4], bf[2];
#pragma unroll
    for (int mi = 0; mi < 4; mi++)
      af[mi] = __builtin_bit_cast(bf16x8, *(const ushort8v*)&Xl[mi * 16 + lm][g * 8]);
#pragma unroll
    for (int ni = 0; ni < 2; ni++)
      bf[ni] = __builtin_bit_cast(bf16x8, *(const ushort8v*)&Wl[wv * 32 + ni * 16 + lm][g * 8]);
#pragma unroll
    for (int mi = 0; mi < 4; mi++)
#pragma unroll
      for (int ni = 0; ni < 2; ni++)
        acc[mi][ni] = __builtin_amdgcn_mfma_f32_16x16x32_bf16(af[mi], bf[ni],
                                                              acc[mi][ni], 0, 0, 0);
    __syncthreads();
  }

  size_t rowbase = (size_t)(b * T + m0);
#pragma unroll
  for (int mi = 0; mi < 4; mi++) {
#pragma unroll
    for (int ni = 0; ni < 2; ni++) {
      int col = nt * 128 + wv * 32 + ni * 16 + lm;
      float bb = bi[col];
#pragma unroll
      for (int r = 0; r < 4; r++) {
        int lr = mi * 16 + 4 * g + r;
        if (lr < valid) {
          size_t idx = (rowbase + lr) * D + col;
          float val = acc[mi][ni][r] + bb;
          if (MODE == 0) out[idx] = add[idx] + val;
          else if (MODE == 1) out[idx] = fmaxf(val, 0.f);
          else out[idx] = out[idx] + val;
        }
      }
    }
  }
}

// ---------------- attention: wave-parallel two-phase online softmax ----------
constexpr int KTP = T + 1;
__global__ __launch_bounds__(256) void k_attn(const float* __restrict__ q,
                                              const float* __restrict__ k,
                                              const float* __restrict__ v,
                                              float* __restrict__ o) {
  int bh = blockIdx.x;
  int b = bh >> 2, h = bh & 3;
  __shared__ unsigned int Kt[HD / 2][KTP];
  __shared__ float Vl[T + 4][HD];
  __shared__ float Ps[4][64];
  __shared__ float Qs[4][HD];
  const size_t base = (size_t)b * T * D + h * HD;
  int tid = threadIdx.x, wave = tid >> 6, lane = tid & 63;

  for (int kk0 = 0; kk0 < T; kk0 += 8) {
    int kk = kk0 + (tid >> 5);
    int d2 = tid & 31;
    float2 kv = ((const float2*)(k + base + (size_t)kk * D))[d2];
    Kt[d2][kk] = f2bf(kv.x) | (f2bf(kv.y) << 16);
  }
  for (int i = tid; i < T * HD; i += 256) {
    int kk = i >> 6, d = i & 63;
    Vl[kk][d] = v[base + (size_t)kk * D + d];
  }
  Vl[T + (tid >> 6)][tid & 63] = 0.f;
  __syncthreads();

  for (int row = wave; row < T; row += 4) {
    Qs[wave][lane] = q[base + (size_t)row * D + lane] * 0.125f;
    float m = -3e38f, l = 0.f, acc = 0.f;
    int nc = (row >> 6) + 1;
    for (int c = 0; c < nc; c++) {
      int kk = (c << 6) + lane;
      bool act = (kk <= row);
      float s = -1e30f;
      if (act) {
        float sum = 0.f;
        const float2* qp = (const float2*)Qs[wave];
#pragma unroll
        for (int d2 = 0; d2 < HD / 2; d2++) {
          unsigned int pk = Kt[d2][kk];
          float2 qv = qp[d2];
          float lo = __uint_as_float(pk << 16);
          float hi = __uint_as_float(pk & 0xffff0000u);
          sum += qv.x * lo + qv.y * hi;
        }
        s = sum;
      }
      float mnew = fmaxf(m, wave_max(s));
      float p = act ? __expf(s - mnew) : 0.f;
      float psum = wave_sum(p);
      float corr = __expf(m - mnew);
      l = l * corr + psum;
      m = mnew;
      Ps[wave][lane] = p;
      int kmax4 = ((row - (c << 6)) + 4) & ~3;
      float a = 0.f;
      const float4* pp = (const float4*)Ps[wave];
      for (int j4 = 0; j4 < (kmax4 >> 2); j4++) {
        float4 pv = pp[j4];
        int kb = (c << 6) + (j4 << 2);
        a += pv.x * Vl[kb + 0][lane];
        a += pv.y * Vl[kb + 1][lane];
        a += pv.z * Vl[kb + 2][lane];
        a += pv.w * Vl[kb + 3][lane];
      }
      acc = acc * corr + a;
    }
    o[base + (size_t)row * D + lane] = acc / l;
  }
}

// ---------------- final LN + pos/neg logits ----------------------------------
__global__ __launch_bounds__(256) void k_final(const float* __restrict__ seqs,
                                               const float* __restrict__ sc,
                                               const float* __restrict__ bi,
                                               const int* __restrict__ pos_seqs,
                                               const int* __restrict__ neg_seqs,
                                               const float* __restrict__ item_emb,
                                               float* __restrict__ out) {
  int tok = blockIdx.x * 4 + (threadIdx.x >> 6);
  int lane = threadIdx.x & 63;
  float4 x = ((const float4*)(seqs + (size_t)tok * D))[lane];
  float mean = wave_sum(x.x + x.y + x.z + x.w) * (1.0f / D);
  float4 c;
  c.x = x.x - mean; c.y = x.y - mean; c.z = x.z - mean; c.w = x.w - mean;
  float var = wave_sum(c.x * c.x + c.y * c.y + c.z * c.z + c.w * c.w) * (1.0f / D);
  float inv = rsqrtf(var + 1e-8f);
  float4 sv = ((const float4*)sc)[lane];
  float4 bv = ((const float4*)bi)[lane];
  float4 f;
  f.x = c.x * inv * sv.x + bv.x;
  f.y = c.y * inv * sv.y + bv.y;
  f.z = c.z * inv * sv.z + bv.z;
  f.w = c.w * inv * sv.w + bv.w;
  int ip = pos_seqs[tok];
  int in_ = neg_seqs[tok];
  float4 pe = ((const float4*)(item_emb + (size_t)ip * D))[lane];
  float4 ne = ((const float4*)(item_emb + (size_t)in_ * D))[lane];
  float dp = wave_sum(f.x * pe.x + f.y * pe.y + f.z * pe.z + f.w * pe.w);
  float dn = wave_sum(f.x * ne.x + f.y * ne.y + f.z * ne.z + f.w * ne.w);
  if (lane == 0) {
    out[tok] = dp;
    out[BT + tok] = dn;
  }
}

}  // namespace

extern "C" void kernel_launch(void* const* d_in, const int* in_sizes, int n_in,
                              void* d_out, int out_size, void* d_ws, size_t ws_size,
                              hipStream_t stream) {
  const int*   log_seqs   = (const int*)d_in[0];
  const int*   pos_seqs   = (const int*)d_in[1];
  const int*   neg_seqs   = (const int*)d_in[2];
  const int*   expert_ids = (const int*)d_in[3];
  const float* item_emb   = (const float*)d_in[4];
  const float* pos_emb    = (const float*)d_in[5];
  const float* attn_ln_s  = (const float*)d_in[6];
  const float* attn_ln_b  = (const float*)d_in[7];
  const float* in_w       = (const float*)d_in[8];
  const float* in_b       = (const float*)d_in[9];
  const float* out_w      = (const float*)d_in[10];
  const float* out_b      = (const float*)d_in[11];
  const float* fwd_ln_s   = (const float*)d_in[12];
  const float* fwd_ln_b   = (const float*)d_in[13];
  const float* ffn_w1     = (const float*)d_in[14];
  const float* ffn_b1     = (const float*)d_in[15];
  const float* ffn_w2     = (const float*)d_in[16];
  const float* ffn_b2     = (const float*)d_in[17];
  const float* last_ln_s  = (const float*)d_in[18];
  const float* last_ln_b  = (const float*)d_in[19];
  float* out = (float*)d_out;

  const size_t N = (size_t)BT * D;
  float* seqs = (float*)d_ws;
  float* qn   = seqs + N;
  float* q    = qn + N;
  float* kbuf = q + N;
  float* vbuf = kbuf + N;
  float* obuf = kbuf;   // alias: attn block reads its K slice into LDS before writing o
  float* hbuf = q;      // alias: FFN hidden reuses q

  k_embed<<<BT, 64, 0, stream>>>(log_seqs, item_emb, pos_emb, seqs);

  for (int l = 0; l < NL; l++) {
    k_ln<<<BT / 4, 256, 0, stream>>>(seqs, qn, attn_ln_s + (size_t)l * D,
                                     attn_ln_b + (size_t)l * D);
    k_gemm_qkv<<<B * MT * 6, 256, 0, stream>>>(
        qn, seqs, in_w + (size_t)l * NE * 3 * D * D, in_b + (size_t)l * NE * 3 * D,
        expert_ids, q, kbuf, vbuf);
    k_attn<<<B * H, 256, 0, stream>>>(q, kbuf, vbuf, obuf);
    k_gemm<0><<<B * MT * 2, 256, 0, stream>>>(
        obuf, out_w + (size_t)l * NE * D * D, out_b + (size_t)l * NE * D, qn, seqs,
        expert_ids);
    k_ln<<<BT / 4, 256, 0, stream>>>(seqs, seqs, fwd_ln_s + (size_t)l * D,
                                     fwd_ln_b + (size_t)l * D);
    k_gemm<1><<<B * MT * 2, 256, 0, stream>>>(
        seqs, ffn_w1 + (size_t)l * D * D, ffn_b1 + (size_t)l * D, nullptr, hbuf,
        expert_ids);
    k_gemm<2><<<B * MT * 2, 256, 0, stream>>>(
        hbuf, ffn_w2 + (size_t)l * D * D, ffn_b2 + (size_t)l * D, nullptr, seqs,
        expert_ids);
  }

  k_final<<<BT / 4, 256, 0, stream>>>(seqs, last_ln_s, last_ln_b, pos_seqs,
                                      neg_seqs, item_emb, out);
}

// Round 4
// 431.703 us; speedup vs baseline: 8.7070x; 2.1367x over previous
//
#include <hip/hip_runtime.h>
#include <hip/hip_bf16.h>

namespace {

constexpr int B  = 128;
constexpr int T  = 200;
constexpr int D  = 256;
constexpr int H  = 4;
constexpr int NE = 4;
constexpr int NL = 2;
constexpr int HD = 64;
constexpr int BT = B * T;

// ---- MFMA GEMM tiling ----
constexpr int BM = 64;
constexpr int BN = 128;
constexpr int BK = 32;
constexpr int MT = (T + BM - 1) / BM;   // 4 M-tiles (last has 8 valid rows)
constexpr int XS = BK + 8;              // padded LDS stride (ushorts) -> 2-way max

typedef __bf16 bf16x8 __attribute__((ext_vector_type(8)));
typedef float f32x4 __attribute__((ext_vector_type(4)));
typedef unsigned short ushort8v __attribute__((ext_vector_type(8)));

__device__ inline float wave_sum(float x) {
#pragma unroll
  for (int off = 32; off > 0; off >>= 1) x += __shfl_xor(x, off);
  return x;
}
__device__ inline unsigned int f2bf(float x) {  // RNE bf16 (as uint)
  unsigned int u = __float_as_uint(x);
  return (u + 0x7fffu + ((u >> 16) & 1u)) >> 16;
}
__device__ inline unsigned short f2bfs(float x) {
  return (unsigned short)f2bf(x);
}
__device__ inline bf16x8 ldb8(const unsigned short* p) {
  return __builtin_bit_cast(bf16x8, *(const ushort8v*)p);
}

// stage ROWS x BK fp32 tile -> bf16 LDS [ROWS][XS]; rows >= valid zero-filled
template <int ROWS>
__device__ inline void stage_tile(const float* __restrict__ src, int ld,
                                  int valid, int k0,
                                  unsigned short (*dst)[XS], int tid) {
#pragma unroll
  for (int p = 0; p < ROWS / 32; p++) {
    int slot = p * 256 + tid;
    int r = slot >> 3, c4 = (slot & 7) << 2;
    float4 v = make_float4(0.f, 0.f, 0.f, 0.f);
    if (r < valid) v = *(const float4*)(src + (size_t)r * ld + k0 + c4);
    ushort4 s;
    s.x = f2bfs(v.x); s.y = f2bfs(v.y); s.z = f2bfs(v.z); s.w = f2bfs(v.w);
    *(ushort4*)&dst[r][c4] = s;
  }
}

// ---------------- embed ----------------
__global__ void k_embed(const int* __restrict__ log_seqs,
                        const float* __restrict__ item_emb,
                        const float* __restrict__ pos_emb,
                        float* __restrict__ seqs) {
  int tok = blockIdx.x;
  int t = tok % T;
  int idx = log_seqs[tok];
  int pos = (idx != 0) ? (t + 1) : 0;
  int lane = threadIdx.x;
  float4 iv = ((const float4*)(item_emb + (size_t)idx * D))[lane];
  float4 pv = ((const float4*)(pos_emb + (size_t)pos * D))[lane];
  float4 r;
  r.x = iv.x * 16.0f + pv.x;
  r.y = iv.y * 16.0f + pv.y;
  r.z = iv.z * 16.0f + pv.z;
  r.w = iv.w * 16.0f + pv.w;
  ((float4*)(seqs + (size_t)tok * D))[lane] = r;
}

// ---------------- layernorm ----------------
__global__ __launch_bounds__(256) void k_ln(const float* __restrict__ in,
                                            float* __restrict__ out,
                                            const float* __restrict__ sc,
                                            const float* __restrict__ bi) {
  int row = blockIdx.x * 4 + (threadIdx.x >> 6);
  int lane = threadIdx.x & 63;
  float4 x = ((const float4*)(in + (size_t)row * D))[lane];
  float mean = wave_sum(x.x + x.y + x.z + x.w) * (1.0f / D);
  float4 c;
  c.x = x.x - mean; c.y = x.y - mean; c.z = x.z - mean; c.w = x.w - mean;
  float var = wave_sum(c.x * c.x + c.y * c.y + c.z * c.z + c.w * c.w) * (1.0f / D);
  float inv = rsqrtf(var + 1e-8f);
  float4 sv = ((const float4*)sc)[lane];
  float4 bv = ((const float4*)bi)[lane];
  float4 r;
  r.x = c.x * inv * sv.x + bv.x;
  r.y = c.y * inv * sv.y + bv.y;
  r.z = c.z * inv * sv.z + bv.z;
  r.w = c.w * inv * sv.w + bv.w;
  ((float4*)(out + (size_t)row * D))[lane] = r;
}

// ---------------- QKV GEMM (bf16 MFMA), routed expert ------------------------
__global__ __launch_bounds__(256) void k_gemm_qkv(
    const float* __restrict__ qn, const float* __restrict__ seqs,
    const float* __restrict__ w, const float* __restrict__ bias,
    const int* __restrict__ expert_ids,
    float* __restrict__ q, float* __restrict__ k, float* __restrict__ v) {
  int bid = blockIdx.x;
  int nt = bid % 6;
  int mt = (bid / 6) % MT;
  int b  = bid / (6 * MT);
  int e = expert_ids[b];
  int m0 = mt * BM;
  int valid = min(BM, T - m0);
  const float* X = (nt < 2) ? qn : seqs;
  const float* Xb = X + (size_t)(b * T + m0) * D;
  const float* Wb = w + (size_t)e * 3 * D * D + (size_t)nt * BN * D;

  __shared__ __align__(16) unsigned short Xl[BM][XS];
  __shared__ __align__(16) unsigned short Wl[BN][XS];
  int tid = threadIdx.x, wv = tid >> 6, lane = tid & 63;
  int g = lane >> 4, lm = lane & 15;

  f32x4 acc[4][2];
#pragma unroll
  for (int mi = 0; mi < 4; mi++)
#pragma unroll
    for (int ni = 0; ni < 2; ni++) acc[mi][ni] = (f32x4){0.f, 0.f, 0.f, 0.f};

  for (int kt = 0; kt < D / BK; kt++) {
    stage_tile<BM>(Xb, D, valid, kt * BK, Xl, tid);
    stage_tile<BN>(Wb, D, BN, kt * BK, Wl, tid);
    __syncthreads();
    bf16x8 af[4], bf[2];
#pragma unroll
    for (int mi = 0; mi < 4; mi++)
      af[mi] = ldb8(&Xl[mi * 16 + lm][g * 8]);
#pragma unroll
    for (int ni = 0; ni < 2; ni++)
      bf[ni] = ldb8(&Wl[wv * 32 + ni * 16 + lm][g * 8]);
#pragma unroll
    for (int mi = 0; mi < 4; mi++)
#pragma unroll
      for (int ni = 0; ni < 2; ni++)
        acc[mi][ni] = __builtin_amdgcn_mfma_f32_16x16x32_bf16(af[mi], bf[ni],
                                                              acc[mi][ni], 0, 0, 0);
    __syncthreads();
  }

  float* outb = (nt < 2) ? q : (nt < 4 ? k : v);
  int lc0 = (nt & 1) * 128 + wv * 32;
  size_t rowbase = (size_t)(b * T + m0);
#pragma unroll
  for (int mi = 0; mi < 4; mi++) {
#pragma unroll
    for (int ni = 0; ni < 2; ni++) {
      int col = lc0 + ni * 16 + lm;
      float bb = bias[e * 3 * D + nt * 128 + wv * 32 + ni * 16 + lm];
#pragma unroll
      for (int r = 0; r < 4; r++) {
        int lr = mi * 16 + 4 * g + r;
        if (lr < valid)
          outb[(rowbase + lr) * D + col] = acc[mi][ni][r] + bb;
      }
    }
  }
}

// ---------------- generic 256x256 GEMM (bf16 MFMA) ---------------------------
// MODE 0: out = add + X@W_e^T + b_e   (out-proj, routed expert)
// MODE 1: out = relu(X@W^T + b)       (FFN1)
// MODE 2: out = out + X@W^T + b       (FFN2 residual)
template <int MODE>
__global__ __launch_bounds__(256) void k_gemm(
    const float* __restrict__ X, const float* __restrict__ w,
    const float* __restrict__ bias, const float* __restrict__ add,
    float* __restrict__ out, const int* __restrict__ expert_ids) {
  int bid = blockIdx.x;
  int nt = bid & 1;
  int mt = (bid >> 1) % MT;
  int b  = bid / (2 * MT);
  int m0 = mt * BM;
  int valid = min(BM, T - m0);
  const float* W = w;
  const float* bi = bias;
  if (MODE == 0) {
    int e = expert_ids[b];
    W += (size_t)e * D * D;
    bi += (size_t)e * D;
  }
  const float* Xb = X + (size_t)(b * T + m0) * D;
  const float* Wb = W + (size_t)nt * BN * D;

  __shared__ __align__(16) unsigned short Xl[BM][XS];
  __shared__ __align__(16) unsigned short Wl[BN][XS];
  int tid = threadIdx.x, wv = tid >> 6, lane = tid & 63;
  int g = lane >> 4, lm = lane & 15;

  f32x4 acc[4][2];
#pragma unroll
  for (int mi = 0; mi < 4; mi++)
#pragma unroll
    for (int ni = 0; ni < 2; ni++) acc[mi][ni] = (f32x4){0.f, 0.f, 0.f, 0.f};

  for (int kt = 0; kt < D / BK; kt++) {
    stage_tile<BM>(Xb, D, valid, kt * BK, Xl, tid);
    stage_tile<BN>(Wb, D, BN, kt * BK, Wl, tid);
    __syncthreads();
    bf16x8 af[4], bf[2];
#pragma unroll
    for (int mi = 0; mi < 4; mi++)
      af[mi] = ldb8(&Xl[mi * 16 + lm][g * 8]);
#pragma unroll
    for (int ni = 0; ni < 2; ni++)
      bf[ni] = ldb8(&Wl[wv * 32 + ni * 16 + lm][g * 8]);
#pragma unroll
    for (int mi = 0; mi < 4; mi++)
#pragma unroll
      for (int ni = 0; ni < 2; ni++)
        acc[mi][ni] = __builtin_amdgcn_mfma_f32_16x16x32_bf16(af[mi], bf[ni],
                                                              acc[mi][ni], 0, 0, 0);
    __syncthreads();
  }

  size_t rowbase = (size_t)(b * T + m0);
#pragma unroll
  for (int mi = 0; mi < 4; mi++) {
#pragma unroll
    for (int ni = 0; ni < 2; ni++) {
      int col = nt * 128 + wv * 32 + ni * 16 + lm;
      float bb = bi[col];
#pragma unroll
      for (int r = 0; r < 4; r++) {
        int lr = mi * 16 + 4 * g + r;
        if (lr < valid) {
          size_t idx = (rowbase + lr) * D + col;
          float val = acc[mi][ni][r] + bb;
          if (MODE == 0) out[idx] = add[idx] + val;
          else if (MODE == 1) out[idx] = fmaxf(val, 0.f);
          else out[idx] = out[idx] + val;
        }
      }
    }
  }
}

// ---------------- MFMA flash attention --------------------------------------
// One block per (b,h), 4 waves. Swapped-operand scheme:
//   S^T = K · Q^T  (D-layout: col(lane&15)=qrow, row(4g+reg)=key)
//   O^T = V^T · P^T (col=qrow, row=dim)
// Row-softmax reduce = shfl_xor(16/32) across the 4 lane-groups.
constexpr int KROWS = 224;   // 13 tiles * 16 rounded to chunk (7*32)
constexpr int KSS = 72;      // Kl stride (ushorts): 144B, 16B-aligned, 2-way banks
constexpr int VSS = 232;     // Vt stride: 464B, 16B-aligned, 2-way banks
constexpr int PSS = 40;      // Pl stride: 80B, 16B-aligned
__global__ __launch_bounds__(256) void k_attn(const float* __restrict__ q,
                                              const float* __restrict__ k,
                                              const float* __restrict__ v,
                                              float* __restrict__ o) {
  int bh = blockIdx.x;
  int b = bh >> 2, h = bh & 3;
  __shared__ __align__(16) unsigned short Kl[KROWS][KSS];
  __shared__ __align__(16) unsigned short Vt[HD][VSS];
  __shared__ __align__(16) unsigned short Pl[4][16][PSS];
  const size_t base = (size_t)b * T * D + h * HD;
  int tid = threadIdx.x, wave = tid >> 6, lane = tid & 63;
  int g = lane >> 4, lm = lane & 15;

  // stage K (row-major bf16) and V (transposed bf16); zero-fill keys >= T
  for (int p = 0; p < KROWS * 32 / 256; p++) {
    int slot = p * 256 + tid;
    int key = slot >> 5, dp = (slot & 31) << 1;
    float2 kv = make_float2(0.f, 0.f), vv = make_float2(0.f, 0.f);
    if (key < T) {
      kv = *(const float2*)(k + base + (size_t)key * D + dp);
      vv = *(const float2*)(v + base + (size_t)key * D + dp);
    }
    *(unsigned int*)&Kl[key][dp] = f2bf(kv.x) | (f2bf(kv.y) << 16);
    Vt[dp][key] = f2bfs(vv.x);
    Vt[dp + 1][key] = f2bfs(vv.y);
  }
  __syncthreads();

  // serpentine tile schedule: chunks/wave = 13,12,12,12 (4-bit packed, 13=end)
  const unsigned long long SCHED = 0x0189D27AD36BD45CULL;
  unsigned sch = (unsigned)(SCHED >> (wave * 16)) & 0xFFFFu;

  for (int si = 0; si < 4; si++) {
    int qt = (sch >> (si * 4)) & 15;
    if (qt > 12) break;
    int m0 = qt * 16;
    int row = m0 + lm;                       // this lane's query row
    int qrow = min(row, T - 1);              // clamp garbage rows for the load
    // Q fragment (B-operand): lane holds Q[qrow][8g+i + 32*half], scaled
    const float sc = 0.125f * 1.44269504f;   // 1/sqrt(HD) * log2(e)
    const float* qr = q + base + (size_t)qrow * D;
    bf16x8 qf0, qf1;
    {
      float4 x0 = *(const float4*)(qr + 8 * g);
      float4 x1 = *(const float4*)(qr + 8 * g + 4);
      float4 y0 = *(const float4*)(qr + 32 + 8 * g);
      float4 y1 = *(const float4*)(qr + 32 + 8 * g + 4);
      ushort8v u0, u1;
      u0[0] = f2bfs(x0.x * sc); u0[1] = f2bfs(x0.y * sc);
      u0[2] = f2bfs(x0.z * sc); u0[3] = f2bfs(x0.w * sc);
      u0[4] = f2bfs(x1.x * sc); u0[5] = f2bfs(x1.y * sc);
      u0[6] = f2bfs(x1.z * sc); u0[7] = f2bfs(x1.w * sc);
      u1[0] = f2bfs(y0.x * sc); u1[1] = f2bfs(y0.y * sc);
      u1[2] = f2bfs(y0.z * sc); u1[3] = f2bfs(y0.w * sc);
      u1[4] = f2bfs(y1.x * sc); u1[5] = f2bfs(y1.y * sc);
      u1[6] = f2bfs(y1.z * sc); u1[7] = f2bfs(y1.w * sc);
      qf0 = __builtin_bit_cast(bf16x8, u0);
      qf1 = __builtin_bit_cast(bf16x8, u1);
    }

    f32x4 oacc[4];
#pragma unroll
    for (int dt = 0; dt < 4; dt++) oacc[dt] = (f32x4){0.f, 0.f, 0.f, 0.f};
    float mrun = -3e38f, lsum = 0.f;

    int nch = qt / 2 + 1;
    for (int c = 0; c < nch; c++) {
      int kb = c * 32;
      // S^T: two 16-key tiles, contraction over HD in 2 halves
      f32x4 s01[2];
#pragma unroll
      for (int t = 0; t < 2; t++) {
        int krow = kb + t * 16 + lm;
        bf16x8 a0 = ldb8(&Kl[krow][8 * g]);
        bf16x8 a1 = ldb8(&Kl[krow][32 + 8 * g]);
        f32x4 z = (f32x4){0.f, 0.f, 0.f, 0.f};
        z = __builtin_amdgcn_mfma_f32_16x16x32_bf16(a0, qf0, z, 0, 0, 0);
        z = __builtin_amdgcn_mfma_f32_16x16x32_bf16(a1, qf1, z, 0, 0, 0);
        s01[t] = z;
      }
      // causal mask (select: kills NaN from padded K rows) + row max
      float sv[8];
      float mx = -3e38f;
#pragma unroll
      for (int t = 0; t < 2; t++)
#pragma unroll
        for (int r = 0; r < 4; r++) {
          int key = kb + t * 16 + 4 * g + r;
          float x = (key <= row) ? s01[t][r] : -3e38f;
          sv[t * 4 + r] = x;
          mx = fmaxf(mx, x);
        }
      mx = fmaxf(mx, __shfl_xor(mx, 16));
      mx = fmaxf(mx, __shfl_xor(mx, 32));
      float mnew = fmaxf(mrun, mx);
      float corr = __builtin_amdgcn_exp2f(mrun - mnew);
      float ps = 0.f;
      ushort8v pu;
#pragma unroll
      for (int i = 0; i < 8; i++) {
        float p = __builtin_amdgcn_exp2f(sv[i] - mnew);
        ps += p;
        pu[i] = f2bfs(p);
      }
      ps += __shfl_xor(ps, 16);
      ps += __shfl_xor(ps, 32);
      lsum = lsum * corr + ps;
      mrun = mnew;
      // P -> LDS (per-wave private; same-wave RAW handled by compiler waitcnt)
      *(ushort4*)&Pl[wave][lm][4 * g]      = ((ushort4*)&pu)[0];
      *(ushort4*)&Pl[wave][lm][16 + 4 * g] = ((ushort4*)&pu)[1];
      // rescale + PV
#pragma unroll
      for (int dt = 0; dt < 4; dt++)
#pragma unroll
        for (int r = 0; r < 4; r++) oacc[dt][r] *= corr;
      bf16x8 pf = ldb8(&Pl[wave][lm][8 * g]);
#pragma unroll
      for (int dt = 0; dt < 4; dt++) {
        bf16x8 av = ldb8(&Vt[dt * 16 + lm][kb + 8 * g]);
        oacc[dt] = __builtin_amdgcn_mfma_f32_16x16x32_bf16(av, pf, oacc[dt], 0, 0, 0);
      }
    }

    if (row < T) {
      float rinv = 1.0f / lsum;
      float* orow = o + base + (size_t)row * D;
#pragma unroll
      for (int dt = 0; dt < 4; dt++) {
        float4 val;
        val.x = oacc[dt][0] * rinv;
        val.y = oacc[dt][1] * rinv;
        val.z = oacc[dt][2] * rinv;
        val.w = oacc[dt][3] * rinv;
        *(float4*)(orow + dt * 16 + 4 * g) = val;
      }
    }
  }
}

// ---------------- final LN + pos/neg logits ----------------------------------
__global__ __launch_bounds__(256) void k_final(const float* __restrict__ seqs,
                                               const float* __restrict__ sc,
                                               const float* __restrict__ bi,
                                               const int* __restrict__ pos_seqs,
                                               const int* __restrict__ neg_seqs,
                                               const float* __restrict__ item_emb,
                                               float* __restrict__ out) {
  int tok = blockIdx.x * 4 + (threadIdx.x >> 6);
  int lane = threadIdx.x & 63;
  float4 x = ((const float4*)(seqs + (size_t)tok * D))[lane];
  float mean = wave_sum(x.x + x.y + x.z + x.w) * (1.0f / D);
  float4 c;
  c.x = x.x - mean; c.y = x.y - mean; c.z = x.z - mean; c.w = x.w - mean;
  float var = wave_sum(c.x * c.x + c.y * c.y + c.z * c.z + c.w * c.w) * (1.0f / D);
  float inv = rsqrtf(var + 1e-8f);
  float4 sv = ((const float4*)sc)[lane];
  float4 bv = ((const float4*)bi)[lane];
  float4 f;
  f.x = c.x * inv * sv.x + bv.x;
  f.y = c.y * inv * sv.y + bv.y;
  f.z = c.z * inv * sv.z + bv.z;
  f.w = c.w * inv * sv.w + bv.w;
  int ip = pos_seqs[tok];
  int in_ = neg_seqs[tok];
  float4 pe = ((const float4*)(item_emb + (size_t)ip * D))[lane];
  float4 ne = ((const float4*)(item_emb + (size_t)in_ * D))[lane];
  float dp = wave_sum(f.x * pe.x + f.y * pe.y + f.z * pe.z + f.w * pe.w);
  float dn = wave_sum(f.x * ne.x + f.y * ne.y + f.z * ne.z + f.w * ne.w);
  if (lane == 0) {
    out[tok] = dp;
    out[BT + tok] = dn;
  }
}

}  // namespace

extern "C" void kernel_launch(void* const* d_in, const int* in_sizes, int n_in,
                              void* d_out, int out_size, void* d_ws, size_t ws_size,
                              hipStream_t stream) {
  const int*   log_seqs   = (const int*)d_in[0];
  const int*   pos_seqs   = (const int*)d_in[1];
  const int*   neg_seqs   = (const int*)d_in[2];
  const int*   expert_ids = (const int*)d_in[3];
  const float* item_emb   = (const float*)d_in[4];
  const float* pos_emb    = (const float*)d_in[5];
  const float* attn_ln_s  = (const float*)d_in[6];
  const float* attn_ln_b  = (const float*)d_in[7];
  const float* in_w       = (const float*)d_in[8];
  const float* in_b       = (const float*)d_in[9];
  const float* out_w      = (const float*)d_in[10];
  const float* out_b      = (const float*)d_in[11];
  const float* fwd_ln_s   = (const float*)d_in[12];
  const float* fwd_ln_b   = (const float*)d_in[13];
  const float* ffn_w1     = (const float*)d_in[14];
  const float* ffn_b1     = (const float*)d_in[15];
  const float* ffn_w2     = (const float*)d_in[16];
  const float* ffn_b2     = (const float*)d_in[17];
  const float* last_ln_s  = (const float*)d_in[18];
  const float* last_ln_b  = (const float*)d_in[19];
  float* out = (float*)d_out;

  const size_t N = (size_t)BT * D;
  float* seqs = (float*)d_ws;
  float* qn   = seqs + N;
  float* q    = qn + N;
  float* kbuf = q + N;
  float* vbuf = kbuf + N;
  float* obuf = kbuf;   // alias: attn block stages its K slice to LDS before writing o
  float* hbuf = q;      // alias: FFN hidden reuses q

  k_embed<<<BT, 64, 0, stream>>>(log_seqs, item_emb, pos_emb, seqs);

  for (int l = 0; l < NL; l++) {
    k_ln<<<BT / 4, 256, 0, stream>>>(seqs, qn, attn_ln_s + (size_t)l * D,
                                     attn_ln_b + (size_t)l * D);
    k_gemm_qkv<<<B * MT * 6, 256, 0, stream>>>(
        qn, seqs, in_w + (size_t)l * NE * 3 * D * D, in_b + (size_t)l * NE * 3 * D,
        expert_ids, q, kbuf, vbuf);
    k_attn<<<B * H, 256, 0, stream>>>(q, kbuf, vbuf, obuf);
    k_gemm<0><<<B * MT * 2, 256, 0, stream>>>(
        obuf, out_w + (size_t)l * NE * D * D, out_b + (size_t)l * NE * D, qn, seqs,
        expert_ids);
    k_ln<<<BT / 4, 256, 0, stream>>>(seqs, seqs, fwd_ln_s + (size_t)l * D,
                                     fwd_ln_b + (size_t)l * D);
    k_gemm<1><<<B * MT * 2, 256, 0, stream>>>(
        seqs, ffn_w1 + (size_t)l * D * D, ffn_b1 + (size_t)l * D, nullptr, hbuf,
        expert_ids);
    k_gemm<2><<<B * MT * 2, 256, 0, stream>>>(
        hbuf, ffn_w2 + (size_t)l * D * D, ffn_b2 + (size_t)l * D, nullptr, seqs,
        expert_ids);
  }

  k_final<<<BT / 4, 256, 0, stream>>>(seqs, last_ln_s, last_ln_b, pos_seqs,
                                      neg_seqs, item_emb, out);
}

// Round 5
// 275.541 us; speedup vs baseline: 13.6417x; 1.5667x over previous
//
#include <hip/hip_runtime.h>
#include <hip/hip_bf16.h>

namespace {

typedef unsigned short ushort;
constexpr int B  = 128;
constexpr int T  = 200;
constexpr int D  = 256;
constexpr int H  = 4;
constexpr int NE = 4;
constexpr int NL = 2;
constexpr int HD = 64;
constexpr int BT = B * T;

// ---- MFMA GEMM tiling (bf16 pipeline) ----
constexpr int BM = 64;
constexpr int BN = 128;
constexpr int BK = 64;                  // bf16 K-step (128B rows)
constexpr int MT = (T + BM - 1) / BM;   // 4 M-tiles

typedef __bf16 bf16x8 __attribute__((ext_vector_type(8)));
typedef float f32x4 __attribute__((ext_vector_type(4)));
typedef unsigned short ushort8v __attribute__((ext_vector_type(8)));

__device__ inline float wave_sum(float x) {
#pragma unroll
  for (int off = 32; off > 0; off >>= 1) x += __shfl_xor(x, off);
  return x;
}
__device__ inline unsigned int f2bf(float x) {  // RNE bf16 (as uint)
  unsigned int u = __float_as_uint(x);
  return (u + 0x7fffu + ((u >> 16) & 1u)) >> 16;
}
__device__ inline ushort f2bfs(float x) { return (ushort)f2bf(x); }
__device__ inline float bf2f(ushort u) {
  return __uint_as_float((unsigned int)u << 16);
}
__device__ inline bf16x8 ldb8(const ushort* p) {
  return __builtin_bit_cast(bf16x8, *(const ushort8v*)p);
}

// ---------------- fp32 -> bf16 weight conversion ----------------
__global__ void k_cvt(const float* __restrict__ src, ushort* __restrict__ dst,
                      int n4) {
  int i = blockIdx.x * 256 + threadIdx.x;
  if (i < n4) {
    float4 v = ((const float4*)src)[i];
    ushort4 u;
    u.x = f2bfs(v.x); u.y = f2bfs(v.y); u.z = f2bfs(v.z); u.w = f2bfs(v.w);
    ((ushort4*)dst)[i] = u;
  }
}

// ---------------- embed: 4 tokens/block ----------------
__global__ __launch_bounds__(256) void k_embed(const int* __restrict__ log_seqs,
                                               const float* __restrict__ item_emb,
                                               const float* __restrict__ pos_emb,
                                               ushort* __restrict__ seqs) {
  int tok = blockIdx.x * 4 + (threadIdx.x >> 6);
  int lane = threadIdx.x & 63;
  int t = tok % T;
  int idx = log_seqs[tok];
  int pos = (idx != 0) ? (t + 1) : 0;
  float4 iv = ((const float4*)(item_emb + (size_t)idx * D))[lane];
  float4 pv = ((const float4*)(pos_emb + (size_t)pos * D))[lane];
  ushort4 r;
  r.x = f2bfs(iv.x * 16.0f + pv.x);
  r.y = f2bfs(iv.y * 16.0f + pv.y);
  r.z = f2bfs(iv.z * 16.0f + pv.z);
  r.w = f2bfs(iv.w * 16.0f + pv.w);
  ((ushort4*)(seqs + (size_t)tok * D))[lane] = r;
}

// ---------------- layernorm (bf16 io, fp32 math) ----------------
__global__ __launch_bounds__(256) void k_ln(const ushort* __restrict__ in,
                                            ushort* __restrict__ out,
                                            const float* __restrict__ sc,
                                            const float* __restrict__ bi) {
  int row = blockIdx.x * 4 + (threadIdx.x >> 6);
  int lane = threadIdx.x & 63;
  ushort4 xu = ((const ushort4*)(in + (size_t)row * D))[lane];
  float x0 = bf2f(xu.x), x1 = bf2f(xu.y), x2 = bf2f(xu.z), x3 = bf2f(xu.w);
  float mean = wave_sum(x0 + x1 + x2 + x3) * (1.0f / D);
  float c0 = x0 - mean, c1 = x1 - mean, c2 = x2 - mean, c3 = x3 - mean;
  float var = wave_sum(c0 * c0 + c1 * c1 + c2 * c2 + c3 * c3) * (1.0f / D);
  float inv = rsqrtf(var + 1e-8f);
  float4 sv = ((const float4*)sc)[lane];
  float4 bv = ((const float4*)bi)[lane];
  ushort4 r;
  r.x = f2bfs(c0 * inv * sv.x + bv.x);
  r.y = f2bfs(c1 * inv * sv.y + bv.y);
  r.z = f2bfs(c2 * inv * sv.z + bv.z);
  r.w = f2bfs(c3 * inv * sv.w + bv.w);
  ((ushort4*)(out + (size_t)row * D))[lane] = r;
}

// ---- bf16 tile staging with XOR bank swizzle: slot' = slot ^ (row & 7) ----
// tile: [ROWS][64] bf16, 8 16B-slots per 128B row.
template <int ROWS>
__device__ inline void stage_bf16(const ushort* __restrict__ src, int ld,
                                  int valid, int k0, ushort* __restrict__ dst,
                                  int tid) {
#pragma unroll
  for (int p = 0; p < ROWS * 8 / 256; p++) {
    int slot = p * 256 + tid;
    int r = slot >> 3, s_st = slot & 7;
    int s_src = s_st ^ (r & 7);
    int rs = (r < valid) ? r : (valid - 1);   // clamp: finite garbage, masked at C-write
    uint4 w = *(const uint4*)(src + (size_t)rs * ld + k0 + s_src * 8);
    *(uint4*)(dst + r * BK + s_st * 8) = w;
  }
}
__device__ inline bf16x8 frag(const ushort* tile, int row, int slot_log) {
  int s = slot_log ^ (row & 7);
  return ldb8(tile + row * BK + s * 8);
}

// ---------------- QKV GEMM (bf16), routed expert ------------------------
// grid: B*MT*6 ; nt 0-1 -> q (X=qn), 2-3 -> k, 4-5 -> v (X=seqs)
__global__ __launch_bounds__(256) void k_gemm_qkv(
    const ushort* __restrict__ qn, const ushort* __restrict__ seqs,
    const ushort* __restrict__ w, const float* __restrict__ bias,
    const int* __restrict__ expert_ids,
    ushort* __restrict__ q, ushort* __restrict__ k, ushort* __restrict__ v) {
  int bid = blockIdx.x;
  int nt = bid % 6;
  int mt = (bid / 6) % MT;
  int b  = bid / (6 * MT);
  int e = expert_ids[b];
  int m0 = mt * BM;
  int valid = min(BM, T - m0);
  const ushort* X = (nt < 2) ? qn : seqs;
  const ushort* Xb = X + (size_t)(b * T + m0) * D;
  const ushort* Wb = w + (size_t)e * 3 * D * D + (size_t)nt * BN * D;

  __shared__ __align__(16) ushort Xl[BM * BK];
  __shared__ __align__(16) ushort Wl[BN * BK];
  int tid = threadIdx.x, wv = tid >> 6, lane = tid & 63;
  int g = lane >> 4, lm = lane & 15;

  f32x4 acc[4][2];
#pragma unroll
  for (int mi = 0; mi < 4; mi++)
#pragma unroll
    for (int ni = 0; ni < 2; ni++) acc[mi][ni] = (f32x4){0.f, 0.f, 0.f, 0.f};

  for (int kt = 0; kt < D / BK; kt++) {
    stage_bf16<BM>(Xb, D, valid, kt * BK, Xl, tid);
    stage_bf16<BN>(Wb, D, BN, kt * BK, Wl, tid);
    __syncthreads();
    bf16x8 a[4][2], bb[2][2];
#pragma unroll
    for (int mi = 0; mi < 4; mi++)
#pragma unroll
      for (int hh = 0; hh < 2; hh++)
        a[mi][hh] = frag(Xl, mi * 16 + lm, hh * 4 + g);
#pragma unroll
    for (int ni = 0; ni < 2; ni++)
#pragma unroll
      for (int hh = 0; hh < 2; hh++)
        bb[ni][hh] = frag(Wl, wv * 32 + ni * 16 + lm, hh * 4 + g);
#pragma unroll
    for (int mi = 0; mi < 4; mi++)
#pragma unroll
      for (int ni = 0; ni < 2; ni++) {
        acc[mi][ni] = __builtin_amdgcn_mfma_f32_16x16x32_bf16(a[mi][0], bb[ni][0],
                                                              acc[mi][ni], 0, 0, 0);
        acc[mi][ni] = __builtin_amdgcn_mfma_f32_16x16x32_bf16(a[mi][1], bb[ni][1],
                                                              acc[mi][ni], 0, 0, 0);
      }
    __syncthreads();
  }

  ushort* outb = (nt < 2) ? q : (nt < 4 ? k : v);
  size_t rowbase = (size_t)(b * T + m0);
#pragma unroll
  for (int mi = 0; mi < 4; mi++) {
#pragma unroll
    for (int ni = 0; ni < 2; ni++) {
      int col = (nt & 1) * 128 + wv * 32 + ni * 16 + lm;
      float bbv = bias[e * 3 * D + nt * 128 + wv * 32 + ni * 16 + lm];
#pragma unroll
      for (int r = 0; r < 4; r++) {
        int lr = mi * 16 + 4 * g + r;
        if (lr < valid)
          outb[(rowbase + lr) * D + col] = f2bfs(acc[mi][ni][r] + bbv);
      }
    }
  }
}

// ---------------- generic 256x256 GEMM (bf16) ---------------------------
// MODE 0: out = add + X@W_e^T + b_e   (out-proj, routed expert)
// MODE 1: out = relu(X@W^T + b)       (FFN1)
// MODE 2: out = out + X@W^T + b       (FFN2 residual)
template <int MODE>
__global__ __launch_bounds__(256) void k_gemm(
    const ushort* __restrict__ X, const ushort* __restrict__ w,
    const float* __restrict__ bias, const ushort* __restrict__ add,
    ushort* __restrict__ out, const int* __restrict__ expert_ids) {
  int bid = blockIdx.x;
  int nt = bid & 1;
  int mt = (bid >> 1) % MT;
  int b  = bid / (2 * MT);
  int m0 = mt * BM;
  int valid = min(BM, T - m0);
  const ushort* W = w;
  const float* bi = bias;
  if (MODE == 0) {
    int e = expert_ids[b];
    W += (size_t)e * D * D;
    bi += (size_t)e * D;
  }
  const ushort* Xb = X + (size_t)(b * T + m0) * D;
  const ushort* Wb = W + (size_t)nt * BN * D;

  __shared__ __align__(16) ushort Xl[BM * BK];
  __shared__ __align__(16) ushort Wl[BN * BK];
  int tid = threadIdx.x, wv = tid >> 6, lane = tid & 63;
  int g = lane >> 4, lm = lane & 15;

  f32x4 acc[4][2];
#pragma unroll
  for (int mi = 0; mi < 4; mi++)
#pragma unroll
    for (int ni = 0; ni < 2; ni++) acc[mi][ni] = (f32x4){0.f, 0.f, 0.f, 0.f};

  for (int kt = 0; kt < D / BK; kt++) {
    stage_bf16<BM>(Xb, D, valid, kt * BK, Xl, tid);
    stage_bf16<BN>(Wb, D, BN, kt * BK, Wl, tid);
    __syncthreads();
    bf16x8 a[4][2], bb[2][2];
#pragma unroll
    for (int mi = 0; mi < 4; mi++)
#pragma unroll
      for (int hh = 0; hh < 2; hh++)
        a[mi][hh] = frag(Xl, mi * 16 + lm, hh * 4 + g);
#pragma unroll
    for (int ni = 0; ni < 2; ni++)
#pragma unroll
      for (int hh = 0; hh < 2; hh++)
        bb[ni][hh] = frag(Wl, wv * 32 + ni * 16 + lm, hh * 4 + g);
#pragma unroll
    for (int mi = 0; mi < 4; mi++)
#pragma unroll
      for (int ni = 0; ni < 2; ni++) {
        acc[mi][ni] = __builtin_amdgcn_mfma_f32_16x16x32_bf16(a[mi][0], bb[ni][0],
                                                              acc[mi][ni], 0, 0, 0);
        acc[mi][ni] = __builtin_amdgcn_mfma_f32_16x16x32_bf16(a[mi][1], bb[ni][1],
                                                              acc[mi][ni], 0, 0, 0);
      }
    __syncthreads();
  }

  size_t rowbase = (size_t)(b * T + m0);
#pragma unroll
  for (int mi = 0; mi < 4; mi++) {
#pragma unroll
    for (int ni = 0; ni < 2; ni++) {
      int col = nt * 128 + wv * 32 + ni * 16 + lm;
      float bbv = bi[col];
#pragma unroll
      for (int r = 0; r < 4; r++) {
        int lr = mi * 16 + 4 * g + r;
        if (lr < valid) {
          size_t idx = (rowbase + lr) * D + col;
          float val = acc[mi][ni][r] + bbv;
          if (MODE == 0) out[idx] = f2bfs(bf2f(add[idx]) + val);
          else if (MODE == 1) out[idx] = f2bfs(fmaxf(val, 0.f));
          else out[idx] = f2bfs(bf2f(out[idx]) + val);
        }
      }
    }
  }
}

// ---------------- MFMA flash attention (bf16 io) -----------------------------
constexpr int KROWS = 224;
constexpr int KSS = 72;      // Kl stride (ushorts)
constexpr int VSS = 232;     // Vt stride
constexpr int PSS = 40;      // Pl stride
__global__ __launch_bounds__(256) void k_attn(const ushort* __restrict__ q,
                                              const ushort* __restrict__ k,
                                              const ushort* __restrict__ v,
                                              ushort* __restrict__ o) {
  int bh = blockIdx.x;
  int b = bh >> 2, h = bh & 3;
  __shared__ __align__(16) ushort Kl[KROWS][KSS];
  __shared__ __align__(16) ushort Vt[HD][VSS];
  __shared__ __align__(16) ushort Pl[4][16][PSS];
  const size_t base = (size_t)b * T * D + h * HD;
  int tid = threadIdx.x, wave = tid >> 6, lane = tid & 63;
  int g = lane >> 4, lm = lane & 15;

  // stage K rows (16B/thread-slot), zero-fill keys >= T
#pragma unroll
  for (int p = 0; p < 7; p++) {
    int slot = p * 256 + tid;
    int key = slot >> 3, s8 = (slot & 7) << 3;
    uint4 w = make_uint4(0, 0, 0, 0);
    if (key < T) w = *(const uint4*)(k + base + (size_t)key * D + s8);
    *(uint4*)&Kl[key][s8] = w;
  }
  // stage V transposed
#pragma unroll
  for (int p = 0; p < 28; p++) {
    int slot = p * 256 + tid;
    int key = slot >> 5, dp = (slot & 31) << 1;
    unsigned int w = 0;
    if (key < T) w = *(const unsigned int*)(v + base + (size_t)key * D + dp);
    Vt[dp][key] = (ushort)(w & 0xffffu);
    Vt[dp + 1][key] = (ushort)(w >> 16);
  }
  __syncthreads();

  // serpentine tile schedule: chunks/wave = 13,12,12,12 (4-bit packed, 13=end)
  const unsigned long long SCHED = 0x0189D27AD36BD45CULL;
  unsigned sch = (unsigned)(SCHED >> (wave * 16)) & 0xFFFFu;
  const float sc = 0.125f * 1.44269504f;   // 1/sqrt(HD) * log2(e), applied to S

  for (int si = 0; si < 4; si++) {
    int qt = (sch >> (si * 4)) & 15;
    if (qt > 12) break;
    int row = qt * 16 + lm;
    int qrow = min(row, T - 1);
    const ushort* qr = q + base + (size_t)qrow * D;
    bf16x8 qf0 = ldb8(qr + 8 * g);
    bf16x8 qf1 = ldb8(qr + 32 + 8 * g);

    f32x4 oacc[4];
#pragma unroll
    for (int dt = 0; dt < 4; dt++) oacc[dt] = (f32x4){0.f, 0.f, 0.f, 0.f};
    float mrun = -3e38f, lsum = 0.f;

    int nch = qt / 2 + 1;
    for (int c = 0; c < nch; c++) {
      int kb = c * 32;
      f32x4 s01[2];
#pragma unroll
      for (int t = 0; t < 2; t++) {
        int krow = kb + t * 16 + lm;
        bf16x8 a0 = ldb8(&Kl[krow][8 * g]);
        bf16x8 a1 = ldb8(&Kl[krow][32 + 8 * g]);
        f32x4 z = (f32x4){0.f, 0.f, 0.f, 0.f};
        z = __builtin_amdgcn_mfma_f32_16x16x32_bf16(a0, qf0, z, 0, 0, 0);
        z = __builtin_amdgcn_mfma_f32_16x16x32_bf16(a1, qf1, z, 0, 0, 0);
        s01[t] = z;
      }
      float sv[8];
      float mx = -3e38f;
#pragma unroll
      for (int t = 0; t < 2; t++)
#pragma unroll
        for (int r = 0; r < 4; r++) {
          int key = kb + t * 16 + 4 * g + r;
          float x = (key <= row) ? s01[t][r] * sc : -3e38f;
          sv[t * 4 + r] = x;
          mx = fmaxf(mx, x);
        }
      mx = fmaxf(mx, __shfl_xor(mx, 16));
      mx = fmaxf(mx, __shfl_xor(mx, 32));
      float mnew = fmaxf(mrun, mx);
      float corr = __builtin_amdgcn_exp2f(mrun - mnew);
      float ps = 0.f;
      ushort8v pu;
#pragma unroll
      for (int i = 0; i < 8; i++) {
        float p = __builtin_amdgcn_exp2f(sv[i] - mnew);
        ps += p;
        pu[i] = f2bfs(p);
      }
      ps += __shfl_xor(ps, 16);
      ps += __shfl_xor(ps, 32);
      lsum = lsum * corr + ps;
      mrun = mnew;
      *(ushort4*)&Pl[wave][lm][4 * g]      = ((ushort4*)&pu)[0];
      *(ushort4*)&Pl[wave][lm][16 + 4 * g] = ((ushort4*)&pu)[1];
#pragma unroll
      for (int dt = 0; dt < 4; dt++)
#pragma unroll
        for (int r = 0; r < 4; r++) oacc[dt][r] *= corr;
      bf16x8 pf = ldb8(&Pl[wave][lm][8 * g]);
#pragma unroll
      for (int dt = 0; dt < 4; dt++) {
        bf16x8 av = ldb8(&Vt[dt * 16 + lm][kb + 8 * g]);
        oacc[dt] = __builtin_amdgcn_mfma_f32_16x16x32_bf16(av, pf, oacc[dt], 0, 0, 0);
      }
    }

    if (row < T) {
      float rinv = 1.0f / lsum;
      ushort* orow = o + base + (size_t)row * D;
#pragma unroll
      for (int dt = 0; dt < 4; dt++) {
        ushort4 uo;
        uo.x = f2bfs(oacc[dt][0] * rinv);
        uo.y = f2bfs(oacc[dt][1] * rinv);
        uo.z = f2bfs(oacc[dt][2] * rinv);
        uo.w = f2bfs(oacc[dt][3] * rinv);
        *(ushort4*)(orow + dt * 16 + 4 * g) = uo;
      }
    }
  }
}

// ---------------- final LN + pos/neg logits ----------------------------------
__global__ __launch_bounds__(256) void k_final(const ushort* __restrict__ seqs,
                                               const float* __restrict__ sc,
                                               const float* __restrict__ bi,
                                               const int* __restrict__ pos_seqs,
                                               const int* __restrict__ neg_seqs,
                                               const float* __restrict__ item_emb,
                                               float* __restrict__ out) {
  int tok = blockIdx.x * 4 + (threadIdx.x >> 6);
  int lane = threadIdx.x & 63;
  ushort4 xu = ((const ushort4*)(seqs + (size_t)tok * D))[lane];
  float x0 = bf2f(xu.x), x1 = bf2f(xu.y), x2 = bf2f(xu.z), x3 = bf2f(xu.w);
  float mean = wave_sum(x0 + x1 + x2 + x3) * (1.0f / D);
  float c0 = x0 - mean, c1 = x1 - mean, c2 = x2 - mean, c3 = x3 - mean;
  float var = wave_sum(c0 * c0 + c1 * c1 + c2 * c2 + c3 * c3) * (1.0f / D);
  float inv = rsqrtf(var + 1e-8f);
  float4 sv = ((const float4*)sc)[lane];
  float4 bv = ((const float4*)bi)[lane];
  float f0 = c0 * inv * sv.x + bv.x;
  float f1 = c1 * inv * sv.y + bv.y;
  float f2 = c2 * inv * sv.z + bv.z;
  float f3 = c3 * inv * sv.w + bv.w;
  int ip = pos_seqs[tok];
  int in_ = neg_seqs[tok];
  float4 pe = ((const float4*)(item_emb + (size_t)ip * D))[lane];
  float4 ne = ((const float4*)(item_emb + (size_t)in_ * D))[lane];
  float dp = wave_sum(f0 * pe.x + f1 * pe.y + f2 * pe.z + f3 * pe.w);
  float dn = wave_sum(f0 * ne.x + f1 * ne.y + f2 * ne.z + f3 * ne.w);
  if (lane == 0) {
    out[tok] = dp;
    out[BT + tok] = dn;
  }
}

}  // namespace

extern "C" void kernel_launch(void* const* d_in, const int* in_sizes, int n_in,
                              void* d_out, int out_size, void* d_ws, size_t ws_size,
                              hipStream_t stream) {
  const int*   log_seqs   = (const int*)d_in[0];
  const int*   pos_seqs   = (const int*)d_in[1];
  const int*   neg_seqs   = (const int*)d_in[2];
  const int*   expert_ids = (const int*)d_in[3];
  const float* item_emb   = (const float*)d_in[4];
  const float* pos_emb    = (const float*)d_in[5];
  const float* attn_ln_s  = (const float*)d_in[6];
  const float* attn_ln_b  = (const float*)d_in[7];
  const float* in_w       = (const float*)d_in[8];
  const float* in_b       = (const float*)d_in[9];
  const float* out_w      = (const float*)d_in[10];
  const float* out_b      = (const float*)d_in[11];
  const float* fwd_ln_s   = (const float*)d_in[12];
  const float* fwd_ln_b   = (const float*)d_in[13];
  const float* ffn_w1     = (const float*)d_in[14];
  const float* ffn_b1     = (const float*)d_in[15];
  const float* ffn_w2     = (const float*)d_in[16];
  const float* ffn_b2     = (const float*)d_in[17];
  const float* last_ln_s  = (const float*)d_in[18];
  const float* last_ln_b  = (const float*)d_in[19];
  float* out = (float*)d_out;

  const size_t N = (size_t)BT * D;
  ushort* seqs = (ushort*)d_ws;
  ushort* qn   = seqs + N;
  ushort* q    = qn + N;
  ushort* kbuf = q + N;
  ushort* vbuf = kbuf + N;
  ushort* obuf = kbuf;   // alias: attn stages K to LDS before writing o
  ushort* hbuf = q;      // alias: FFN hidden reuses q
  ushort* wqkv = vbuf + N;                               // [NL][NE][3D][D]
  ushort* wout = wqkv + (size_t)NL * NE * 3 * D * D;     // [NL][NE][D][D]
  ushort* wf1  = wout + (size_t)NL * NE * D * D;         // [NL][D][D]
  ushort* wf2  = wf1 + (size_t)NL * D * D;               // [NL][D][D]

  // weight pre-conversion (bf16)
  {
    int n4a = NL * NE * 3 * D * D / 4;
    int n4b = NL * NE * D * D / 4;
    int n4c = NL * D * D / 4;
    k_cvt<<<(n4a + 255) / 256, 256, 0, stream>>>(in_w, wqkv, n4a);
    k_cvt<<<(n4b + 255) / 256, 256, 0, stream>>>(out_w, wout, n4b);
    k_cvt<<<(n4c + 255) / 256, 256, 0, stream>>>(ffn_w1, wf1, n4c);
    k_cvt<<<(n4c + 255) / 256, 256, 0, stream>>>(ffn_w2, wf2, n4c);
  }

  k_embed<<<BT / 4, 256, 0, stream>>>(log_seqs, item_emb, pos_emb, seqs);

  for (int l = 0; l < NL; l++) {
    k_ln<<<BT / 4, 256, 0, stream>>>(seqs, qn, attn_ln_s + (size_t)l * D,
                                     attn_ln_b + (size_t)l * D);
    k_gemm_qkv<<<B * MT * 6, 256, 0, stream>>>(
        qn, seqs, wqkv + (size_t)l * NE * 3 * D * D,
        in_b + (size_t)l * NE * 3 * D, expert_ids, q, kbuf, vbuf);
    k_attn<<<B * H, 256, 0, stream>>>(q, kbuf, vbuf, obuf);
    k_gemm<0><<<B * MT * 2, 256, 0, stream>>>(
        obuf, wout + (size_t)l * NE * D * D, out_b + (size_t)l * NE * D, qn, seqs,
        expert_ids);
    k_ln<<<BT / 4, 256, 0, stream>>>(seqs, seqs, fwd_ln_s + (size_t)l * D,
                                     fwd_ln_b + (size_t)l * D);
    k_gemm<1><<<B * MT * 2, 256, 0, stream>>>(
        seqs, wf1 + (size_t)l * D * D, ffn_b1 + (size_t)l * D, nullptr, hbuf,
        expert_ids);
    k_gemm<2><<<B * MT * 2, 256, 0, stream>>>(
        hbuf, wf2 + (size_t)l * D * D, ffn_b2 + (size_t)l * D, nullptr, seqs,
        expert_ids);
  }

  k_final<<<BT / 4, 256, 0, stream>>>(seqs, last_ln_s, last_ln_b, pos_seqs,
                                      neg_seqs, item_emb, out);
}

// Round 6
// 261.683 us; speedup vs baseline: 14.3641x; 1.0530x over previous
//
#include <hip/hip_runtime.h>
#include <hip/hip_bf16.h>

namespace {

typedef unsigned short ushort;
constexpr int B  = 128;
constexpr int T  = 200;
constexpr int D  = 256;
constexpr int H  = 4;
constexpr int NE = 4;
constexpr int NL = 2;
constexpr int HD = 64;
constexpr int BT = B * T;

constexpr int BM = 64;
constexpr int BK = 64;                  // bf16 K-step (128B rows)
constexpr int MT = (T + BM - 1) / BM;   // 4 M-tiles
constexpr int HS = 264;                 // FFN hidden LDS stride (2-way banks)

typedef __bf16 bf16x8 __attribute__((ext_vector_type(8)));
typedef float f32x4 __attribute__((ext_vector_type(4)));
typedef unsigned short ushort8v __attribute__((ext_vector_type(8)));

__device__ inline float wave_sum(float x) {
#pragma unroll
  for (int off = 32; off > 0; off >>= 1) x += __shfl_xor(x, off);
  return x;
}
__device__ inline unsigned int f2bf(float x) {  // RNE bf16 (as uint)
  unsigned int u = __float_as_uint(x);
  return (u + 0x7fffu + ((u >> 16) & 1u)) >> 16;
}
__device__ inline ushort f2bfs(float x) { return (ushort)f2bf(x); }
__device__ inline float bf2f(ushort u) {
  return __uint_as_float((unsigned int)u << 16);
}
__device__ inline bf16x8 ldb8(const ushort* p) {
  return __builtin_bit_cast(bf16x8, *(const ushort8v*)p);
}

// ---------------- fp32 -> bf16 weight conversion ----------------
__global__ void k_cvt(const float* __restrict__ src, ushort* __restrict__ dst,
                      int n4) {
  int i = blockIdx.x * 256 + threadIdx.x;
  if (i < n4) {
    float4 v = ((const float4*)src)[i];
    ushort4 u;
    u.x = f2bfs(v.x); u.y = f2bfs(v.y); u.z = f2bfs(v.z); u.w = f2bfs(v.w);
    ((ushort4*)dst)[i] = u;
  }
}

// ---------------- embed + attn-LN(layer0): 4 tokens/block ----------------
__global__ __launch_bounds__(256) void k_embed_ln(
    const int* __restrict__ log_seqs, const float* __restrict__ item_emb,
    const float* __restrict__ pos_emb, const float* __restrict__ lns,
    const float* __restrict__ lnb, ushort* __restrict__ seqs,
    ushort* __restrict__ qn) {
  int tok = blockIdx.x * 4 + (threadIdx.x >> 6);
  int lane = threadIdx.x & 63;
  int t = tok % T;
  int idx = log_seqs[tok];
  int pos = (idx != 0) ? (t + 1) : 0;
  float4 iv = ((const float4*)(item_emb + (size_t)idx * D))[lane];
  float4 pv = ((const float4*)(pos_emb + (size_t)pos * D))[lane];
  float v0 = iv.x * 16.0f + pv.x;
  float v1 = iv.y * 16.0f + pv.y;
  float v2 = iv.z * 16.0f + pv.z;
  float v3 = iv.w * 16.0f + pv.w;
  ushort4 r;
  r.x = f2bfs(v0); r.y = f2bfs(v1); r.z = f2bfs(v2); r.w = f2bfs(v3);
  ((ushort4*)(seqs + (size_t)tok * D))[lane] = r;
  float mean = wave_sum(v0 + v1 + v2 + v3) * (1.0f / D);
  float c0 = v0 - mean, c1 = v1 - mean, c2 = v2 - mean, c3 = v3 - mean;
  float var = wave_sum(c0 * c0 + c1 * c1 + c2 * c2 + c3 * c3) * (1.0f / D);
  float inv = rsqrtf(var + 1e-8f);
  float4 sv = ((const float4*)lns)[lane];
  float4 bv = ((const float4*)lnb)[lane];
  ushort4 o;
  o.x = f2bfs(c0 * inv * sv.x + bv.x);
  o.y = f2bfs(c1 * inv * sv.y + bv.y);
  o.z = f2bfs(c2 * inv * sv.z + bv.z);
  o.w = f2bfs(c3 * inv * sv.w + bv.w);
  ((ushort4*)(qn + (size_t)tok * D))[lane] = o;
}

// ---- bf16 tile staging with XOR bank swizzle: slot' = slot ^ (row & 7) ----
template <int ROWS>
__device__ inline void stage_bf16(const ushort* __restrict__ src, int ld,
                                  int valid, int k0, ushort* __restrict__ dst,
                                  int tid) {
#pragma unroll
  for (int p = 0; p < ROWS * 8 / 256; p++) {
    int slot = p * 256 + tid;
    int r = slot >> 3, s_st = slot & 7;
    int s_src = s_st ^ (r & 7);
    int rs = (r < valid) ? r : (valid - 1);   // clamp: finite garbage, masked later
    uint4 w = *(const uint4*)(src + (size_t)rs * ld + k0 + s_src * 8);
    *(uint4*)(dst + r * BK + s_st * 8) = w;
  }
}
__device__ inline bf16x8 frag(const ushort* tile, int row, int slot_log) {
  int s = slot_log ^ (row & 7);
  return ldb8(tile + row * BK + s * 8);
}

// ---------------- QKV GEMM (bf16), routed expert, XCD-chunked ---------------
__global__ __launch_bounds__(256) void k_gemm_qkv(
    const ushort* __restrict__ qn, const ushort* __restrict__ seqs,
    const ushort* __restrict__ w, const float* __restrict__ bias,
    const int* __restrict__ expert_ids,
    ushort* __restrict__ q, ushort* __restrict__ k, ushort* __restrict__ v) {
  // chunked XCD swizzle: 6 sibling blocks (same b,mt) land on the same XCD L2
  constexpr int NWG = B * MT * 6;   // 3072, %8==0
  int phys = blockIdx.x;
  int bid = (phys & 7) * (NWG >> 3) + (phys >> 3);
  int nt = bid % 6;
  int mt = (bid / 6) % MT;
  int b  = bid / (6 * MT);
  int e = expert_ids[b];
  int m0 = mt * BM;
  int valid = min(BM, T - m0);
  const ushort* X = (nt < 2) ? qn : seqs;
  const ushort* Xb = X + (size_t)(b * T + m0) * D;
  const ushort* Wb = w + (size_t)e * 3 * D * D + (size_t)nt * 128 * D;

  __shared__ __align__(16) ushort Xl[BM * BK];
  __shared__ __align__(16) ushort Wl[128 * BK];
  int tid = threadIdx.x, wv = tid >> 6, lane = tid & 63;
  int g = lane >> 4, lm = lane & 15;

  f32x4 acc[4][2];
#pragma unroll
  for (int mi = 0; mi < 4; mi++)
#pragma unroll
    for (int ni = 0; ni < 2; ni++) acc[mi][ni] = (f32x4){0.f, 0.f, 0.f, 0.f};

  for (int kt = 0; kt < D / BK; kt++) {
    stage_bf16<BM>(Xb, D, valid, kt * BK, Xl, tid);
    stage_bf16<128>(Wb, D, 128, kt * BK, Wl, tid);
    __syncthreads();
    bf16x8 a[4][2], bb[2][2];
#pragma unroll
    for (int mi = 0; mi < 4; mi++)
#pragma unroll
      for (int hh = 0; hh < 2; hh++)
        a[mi][hh] = frag(Xl, mi * 16 + lm, hh * 4 + g);
#pragma unroll
    for (int ni = 0; ni < 2; ni++)
#pragma unroll
      for (int hh = 0; hh < 2; hh++)
        bb[ni][hh] = frag(Wl, wv * 32 + ni * 16 + lm, hh * 4 + g);
#pragma unroll
    for (int mi = 0; mi < 4; mi++)
#pragma unroll
      for (int ni = 0; ni < 2; ni++) {
        acc[mi][ni] = __builtin_amdgcn_mfma_f32_16x16x32_bf16(a[mi][0], bb[ni][0],
                                                              acc[mi][ni], 0, 0, 0);
        acc[mi][ni] = __builtin_amdgcn_mfma_f32_16x16x32_bf16(a[mi][1], bb[ni][1],
                                                              acc[mi][ni], 0, 0, 0);
      }
    __syncthreads();
  }

  ushort* outb = (nt < 2) ? q : (nt < 4 ? k : v);
  size_t rowbase = (size_t)(b * T + m0);
#pragma unroll
  for (int mi = 0; mi < 4; mi++) {
#pragma unroll
    for (int ni = 0; ni < 2; ni++) {
      int col = (nt & 1) * 128 + wv * 32 + ni * 16 + lm;
      float bbv = bias[e * 3 * D + nt * 128 + wv * 32 + ni * 16 + lm];
#pragma unroll
      for (int r = 0; r < 4; r++) {
        int lr = mi * 16 + 4 * g + r;
        if (lr < valid)
          outb[(rowbase + lr) * D + col] = f2bfs(acc[mi][ni][r] + bbv);
      }
    }
  }
}

// ---------------- out-proj GEMM (BN=256/block) + residual + fwd-LN ----------
__global__ __launch_bounds__(256) void k_oproj(
    const ushort* __restrict__ o, const ushort* __restrict__ qn,
    const ushort* __restrict__ w, const float* __restrict__ bo,
    const float* __restrict__ lns, const float* __restrict__ lnb,
    const int* __restrict__ expert_ids, ushort* __restrict__ seqs) {
  int bid = blockIdx.x;
  int mt = bid % MT;
  int b  = bid / MT;
  int e = expert_ids[b];
  int m0 = mt * BM;
  int valid = min(BM, T - m0);
  const ushort* Xb = o + (size_t)(b * T + m0) * D;
  const ushort* Wb = w + (size_t)e * D * D;

  __shared__ __align__(16) ushort Xl[BM * BK];
  __shared__ __align__(16) ushort Wl[D * BK];
  __shared__ float rs_sum[BM][4];
  __shared__ float rs_sq[BM][4];
  int tid = threadIdx.x, wv = tid >> 6, lane = tid & 63;
  int g = lane >> 4, lm = lane & 15;

  f32x4 acc[4][4];
#pragma unroll
  for (int mi = 0; mi < 4; mi++)
#pragma unroll
    for (int ni = 0; ni < 4; ni++) acc[mi][ni] = (f32x4){0.f, 0.f, 0.f, 0.f};

  for (int kt = 0; kt < D / BK; kt++) {
    stage_bf16<BM>(Xb, D, valid, kt * BK, Xl, tid);
    stage_bf16<D>(Wb, D, D, kt * BK, Wl, tid);
    __syncthreads();
    bf16x8 a[4][2], bb[4][2];
#pragma unroll
    for (int mi = 0; mi < 4; mi++)
#pragma unroll
      for (int hh = 0; hh < 2; hh++)
        a[mi][hh] = frag(Xl, mi * 16 + lm, hh * 4 + g);
#pragma unroll
    for (int ni = 0; ni < 4; ni++)
#pragma unroll
      for (int hh = 0; hh < 2; hh++)
        bb[ni][hh] = frag(Wl, wv * 64 + ni * 16 + lm, hh * 4 + g);
#pragma unroll
    for (int mi = 0; mi < 4; mi++)
#pragma unroll
      for (int ni = 0; ni < 4; ni++) {
        acc[mi][ni] = __builtin_amdgcn_mfma_f32_16x16x32_bf16(a[mi][0], bb[ni][0],
                                                              acc[mi][ni], 0, 0, 0);
        acc[mi][ni] = __builtin_amdgcn_mfma_f32_16x16x32_bf16(a[mi][1], bb[ni][1],
                                                              acc[mi][ni], 0, 0, 0);
      }
    __syncthreads();
  }

  size_t rowbase = (size_t)(b * T + m0);
  // add bias + qn residual (fp32)
#pragma unroll
  for (int ni = 0; ni < 4; ni++) {
    int col = wv * 64 + ni * 16 + lm;
    float bbv = bo[e * D + col];
#pragma unroll
    for (int mi = 0; mi < 4; mi++)
#pragma unroll
      for (int r = 0; r < 4; r++) {
        int lr = mi * 16 + 4 * g + r;
        int lrc = (lr < valid) ? lr : (valid - 1);
        acc[mi][ni][r] += bbv + bf2f(qn[(rowbase + lrc) * D + col]);
      }
  }
  // row stats (mean/var over 256 cols)
#pragma unroll
  for (int mi = 0; mi < 4; mi++)
#pragma unroll
    for (int r = 0; r < 4; r++) {
      float s = 0.f, q2 = 0.f;
#pragma unroll
      for (int ni = 0; ni < 4; ni++) {
        float x = acc[mi][ni][r];
        s += x; q2 += x * x;
      }
#pragma unroll
      for (int off = 1; off < 16; off <<= 1) {
        s += __shfl_xor(s, off);
        q2 += __shfl_xor(q2, off);
      }
      if (lm == 0) {
        int row = mi * 16 + 4 * g + r;
        rs_sum[row][wv] = s;
        rs_sq[row][wv] = q2;
      }
    }
  __syncthreads();
  float scv[4], bcv[4];
#pragma unroll
  for (int ni = 0; ni < 4; ni++) {
    int col = wv * 64 + ni * 16 + lm;
    scv[ni] = lns[col];
    bcv[ni] = lnb[col];
  }
#pragma unroll
  for (int mi = 0; mi < 4; mi++)
#pragma unroll
    for (int r = 0; r < 4; r++) {
      int lr = mi * 16 + 4 * g + r;
      float4 s4 = *(const float4*)rs_sum[lr];
      float4 q4 = *(const float4*)rs_sq[lr];
      float mean = (s4.x + s4.y + s4.z + s4.w) * (1.0f / D);
      float var = (q4.x + q4.y + q4.z + q4.w) * (1.0f / D) - mean * mean;
      float rstd = rsqrtf(fmaxf(var, 0.f) + 1e-8f);
      if (lr < valid) {
#pragma unroll
        for (int ni = 0; ni < 4; ni++) {
          int col = wv * 64 + ni * 16 + lm;
          float lnv = (acc[mi][ni][r] - mean) * rstd * scv[ni] + bcv[ni];
          seqs[(rowbase + lr) * D + col] = f2bfs(lnv);
        }
      }
    }
}

// ---------------- fused FFN: h=relu(X@W1+b1) in LDS; out=X+h@W2+b2; +attnLN --
__global__ __launch_bounds__(256) void k_ffn(
    const ushort* __restrict__ xin, const ushort* __restrict__ w1,
    const float* __restrict__ b1, const ushort* __restrict__ w2,
    const float* __restrict__ b2, const float* __restrict__ lns,
    const float* __restrict__ lnb, ushort* __restrict__ seqs,
    ushort* __restrict__ qn) {
  int bid = blockIdx.x;
  int mt = bid % MT;
  int b  = bid / MT;
  int m0 = mt * BM;
  int valid = min(BM, T - m0);
  const ushort* Xb = xin + (size_t)(b * T + m0) * D;

  __shared__ __align__(16) ushort Xl[BM * BK];
  __shared__ __align__(16) ushort Wl[D * BK];
  __shared__ __align__(16) ushort hl[BM * HS];
  __shared__ float rs_sum[BM][4];
  __shared__ float rs_sq[BM][4];
  int tid = threadIdx.x, wv = tid >> 6, lane = tid & 63;
  int g = lane >> 4, lm = lane & 15;
  size_t rowbase = (size_t)(b * T + m0);

  f32x4 acc[4][4];
#pragma unroll
  for (int mi = 0; mi < 4; mi++)
#pragma unroll
    for (int ni = 0; ni < 4; ni++) acc[mi][ni] = (f32x4){0.f, 0.f, 0.f, 0.f};

  // GEMM1: h = relu(X @ W1^T + b1)
  for (int kt = 0; kt < D / BK; kt++) {
    stage_bf16<BM>(Xb, D, valid, kt * BK, Xl, tid);
    stage_bf16<D>(w1, D, D, kt * BK, Wl, tid);
    __syncthreads();
    bf16x8 a[4][2], bb[4][2];
#pragma unroll
    for (int mi = 0; mi < 4; mi++)
#pragma unroll
      for (int hh = 0; hh < 2; hh++)
        a[mi][hh] = frag(Xl, mi * 16 + lm, hh * 4 + g);
#pragma unroll
    for (int ni = 0; ni < 4; ni++)
#pragma unroll
      for (int hh = 0; hh < 2; hh++)
        bb[ni][hh] = frag(Wl, wv * 64 + ni * 16 + lm, hh * 4 + g);
#pragma unroll
    for (int mi = 0; mi < 4; mi++)
#pragma unroll
      for (int ni = 0; ni < 4; ni++) {
        acc[mi][ni] = __builtin_amdgcn_mfma_f32_16x16x32_bf16(a[mi][0], bb[ni][0],
                                                              acc[mi][ni], 0, 0, 0);
        acc[mi][ni] = __builtin_amdgcn_mfma_f32_16x16x32_bf16(a[mi][1], bb[ni][1],
                                                              acc[mi][ni], 0, 0, 0);
      }
    __syncthreads();
  }
  // write h (bf16) to LDS
#pragma unroll
  for (int ni = 0; ni < 4; ni++) {
    int col = wv * 64 + ni * 16 + lm;
    float bbv = b1[col];
#pragma unroll
    for (int mi = 0; mi < 4; mi++)
#pragma unroll
      for (int r = 0; r < 4; r++) {
        int row = mi * 16 + 4 * g + r;
        hl[row * HS + col] = f2bfs(fmaxf(acc[mi][ni][r] + bbv, 0.f));
      }
  }
  // GEMM2: out = X + h @ W2^T + b2
#pragma unroll
  for (int mi = 0; mi < 4; mi++)
#pragma unroll
    for (int ni = 0; ni < 4; ni++) acc[mi][ni] = (f32x4){0.f, 0.f, 0.f, 0.f};
  for (int kt = 0; kt < D / BK; kt++) {
    stage_bf16<D>(w2, D, D, kt * BK, Wl, tid);
    __syncthreads();
    bf16x8 a[4][2], bb[4][2];
#pragma unroll
    for (int mi = 0; mi < 4; mi++)
#pragma unroll
      for (int hh = 0; hh < 2; hh++)
        a[mi][hh] = ldb8(&hl[(mi * 16 + lm) * HS + kt * BK + hh * 32 + 8 * g]);
#pragma unroll
    for (int ni = 0; ni < 4; ni++)
#pragma unroll
      for (int hh = 0; hh < 2; hh++)
        bb[ni][hh] = frag(Wl, wv * 64 + ni * 16 + lm, hh * 4 + g);
#pragma unroll
    for (int mi = 0; mi < 4; mi++)
#pragma unroll
      for (int ni = 0; ni < 4; ni++) {
        acc[mi][ni] = __builtin_amdgcn_mfma_f32_16x16x32_bf16(a[mi][0], bb[ni][0],
                                                              acc[mi][ni], 0, 0, 0);
        acc[mi][ni] = __builtin_amdgcn_mfma_f32_16x16x32_bf16(a[mi][1], bb[ni][1],
                                                              acc[mi][ni], 0, 0, 0);
      }
    __syncthreads();
  }
  // bias + residual (fp32)
#pragma unroll
  for (int ni = 0; ni < 4; ni++) {
    int col = wv * 64 + ni * 16 + lm;
    float bbv = b2[col];
#pragma unroll
    for (int mi = 0; mi < 4; mi++)
#pragma unroll
      for (int r = 0; r < 4; r++) {
        int lr = mi * 16 + 4 * g + r;
        int lrc = (lr < valid) ? lr : (valid - 1);
        acc[mi][ni][r] += bbv + bf2f(xin[(rowbase + lrc) * D + col]);
      }
  }
  // row stats for next-layer attn LN
#pragma unroll
  for (int mi = 0; mi < 4; mi++)
#pragma unroll
    for (int r = 0; r < 4; r++) {
      float s = 0.f, q2 = 0.f;
#pragma unroll
      for (int ni = 0; ni < 4; ni++) {
        float x = acc[mi][ni][r];
        s += x; q2 += x * x;
      }
#pragma unroll
      for (int off = 1; off < 16; off <<= 1) {
        s += __shfl_xor(s, off);
        q2 += __shfl_xor(q2, off);
      }
      if (lm == 0) {
        int row = mi * 16 + 4 * g + r;
        rs_sum[row][wv] = s;
        rs_sq[row][wv] = q2;
      }
    }
  __syncthreads();
  float scv[4], bcv[4];
#pragma unroll
  for (int ni = 0; ni < 4; ni++) {
    int col = wv * 64 + ni * 16 + lm;
    scv[ni] = lns[col];
    bcv[ni] = lnb[col];
  }
#pragma unroll
  for (int mi = 0; mi < 4; mi++)
#pragma unroll
    for (int r = 0; r < 4; r++) {
      int lr = mi * 16 + 4 * g + r;
      float4 s4 = *(const float4*)rs_sum[lr];
      float4 q4 = *(const float4*)rs_sq[lr];
      float mean = (s4.x + s4.y + s4.z + s4.w) * (1.0f / D);
      float var = (q4.x + q4.y + q4.z + q4.w) * (1.0f / D) - mean * mean;
      float rstd = rsqrtf(fmaxf(var, 0.f) + 1e-8f);
      if (lr < valid) {
#pragma unroll
        for (int ni = 0; ni < 4; ni++) {
          int col = wv * 64 + ni * 16 + lm;
          float val = acc[mi][ni][r];
          size_t idx = (rowbase + lr) * D + col;
          seqs[idx] = f2bfs(val);
          qn[idx] = f2bfs((val - mean) * rstd * scv[ni] + bcv[ni]);
        }
      }
    }
}

// ---------------- MFMA flash attention (bf16 io) -----------------------------
constexpr int KROWS = 224;
constexpr int KSS = 72;
constexpr int VSS = 232;
constexpr int PSS = 40;
__global__ __launch_bounds__(256) void k_attn(const ushort* __restrict__ q,
                                              const ushort* __restrict__ k,
                                              const ushort* __restrict__ v,
                                              ushort* __restrict__ o) {
  int bh = blockIdx.x;
  int b = bh >> 2, h = bh & 3;
  __shared__ __align__(16) ushort Kl[KROWS][KSS];
  __shared__ __align__(16) ushort Vt[HD][VSS];
  __shared__ __align__(16) ushort Pl[4][16][PSS];
  const size_t base = (size_t)b * T * D + h * HD;
  int tid = threadIdx.x, wave = tid >> 6, lane = tid & 63;
  int g = lane >> 4, lm = lane & 15;

#pragma unroll
  for (int p = 0; p < 7; p++) {
    int slot = p * 256 + tid;
    int key = slot >> 3, s8 = (slot & 7) << 3;
    uint4 w = make_uint4(0, 0, 0, 0);
    if (key < T) w = *(const uint4*)(k + base + (size_t)key * D + s8);
    *(uint4*)&Kl[key][s8] = w;
  }
#pragma unroll
  for (int p = 0; p < 28; p++) {
    int slot = p * 256 + tid;
    int key = slot >> 5, dp = (slot & 31) << 1;
    unsigned int w = 0;
    if (key < T) w = *(const unsigned int*)(v + base + (size_t)key * D + dp);
    Vt[dp][key] = (ushort)(w & 0xffffu);
    Vt[dp + 1][key] = (ushort)(w >> 16);
  }
  __syncthreads();

  const unsigned long long SCHED = 0x0189D27AD36BD45CULL;
  unsigned sch = (unsigned)(SCHED >> (wave * 16)) & 0xFFFFu;
  const float sc = 0.125f * 1.44269504f;

  for (int si = 0; si < 4; si++) {
    int qt = (sch >> (si * 4)) & 15;
    if (qt > 12) break;
    int row = qt * 16 + lm;
    int qrow = min(row, T - 1);
    const ushort* qr = q + base + (size_t)qrow * D;
    bf16x8 qf0 = ldb8(qr + 8 * g);
    bf16x8 qf1 = ldb8(qr + 32 + 8 * g);

    f32x4 oacc[4];
#pragma unroll
    for (int dt = 0; dt < 4; dt++) oacc[dt] = (f32x4){0.f, 0.f, 0.f, 0.f};
    float mrun = -3e38f, lsum = 0.f;

    int nch = qt / 2 + 1;
    for (int c = 0; c < nch; c++) {
      int kb = c * 32;
      f32x4 s01[2];
#pragma unroll
      for (int t = 0; t < 2; t++) {
        int krow = kb + t * 16 + lm;
        bf16x8 a0 = ldb8(&Kl[krow][8 * g]);
        bf16x8 a1 = ldb8(&Kl[krow][32 + 8 * g]);
        f32x4 z = (f32x4){0.f, 0.f, 0.f, 0.f};
        z = __builtin_amdgcn_mfma_f32_16x16x32_bf16(a0, qf0, z, 0, 0, 0);
        z = __builtin_amdgcn_mfma_f32_16x16x32_bf16(a1, qf1, z, 0, 0, 0);
        s01[t] = z;
      }
      float sv[8];
      float mx = -3e38f;
#pragma unroll
      for (int t = 0; t < 2; t++)
#pragma unroll
        for (int r = 0; r < 4; r++) {
          int key = kb + t * 16 + 4 * g + r;
          float x = (key <= row) ? s01[t][r] * sc : -3e38f;
          sv[t * 4 + r] = x;
          mx = fmaxf(mx, x);
        }
      mx = fmaxf(mx, __shfl_xor(mx, 16));
      mx = fmaxf(mx, __shfl_xor(mx, 32));
      float mnew = fmaxf(mrun, mx);
      float corr = __builtin_amdgcn_exp2f(mrun - mnew);
      float ps = 0.f;
      ushort8v pu;
#pragma unroll
      for (int i = 0; i < 8; i++) {
        float p = __builtin_amdgcn_exp2f(sv[i] - mnew);
        ps += p;
        pu[i] = f2bfs(p);
      }
      ps += __shfl_xor(ps, 16);
      ps += __shfl_xor(ps, 32);
      lsum = lsum * corr + ps;
      mrun = mnew;
      *(ushort4*)&Pl[wave][lm][4 * g]      = ((ushort4*)&pu)[0];
      *(ushort4*)&Pl[wave][lm][16 + 4 * g] = ((ushort4*)&pu)[1];
#pragma unroll
      for (int dt = 0; dt < 4; dt++)
#pragma unroll
        for (int r = 0; r < 4; r++) oacc[dt][r] *= corr;
      bf16x8 pf = ldb8(&Pl[wave][lm][8 * g]);
#pragma unroll
      for (int dt = 0; dt < 4; dt++) {
        bf16x8 av = ldb8(&Vt[dt * 16 + lm][kb + 8 * g]);
        oacc[dt] = __builtin_amdgcn_mfma_f32_16x16x32_bf16(av, pf, oacc[dt], 0, 0, 0);
      }
    }

    if (row < T) {
      float rinv = 1.0f / lsum;
      ushort* orow = o + base + (size_t)row * D;
#pragma unroll
      for (int dt = 0; dt < 4; dt++) {
        ushort4 uo;
        uo.x = f2bfs(oacc[dt][0] * rinv);
        uo.y = f2bfs(oacc[dt][1] * rinv);
        uo.z = f2bfs(oacc[dt][2] * rinv);
        uo.w = f2bfs(oacc[dt][3] * rinv);
        *(ushort4*)(orow + dt * 16 + 4 * g) = uo;
      }
    }
  }
}

// ---------------- final LN + pos/neg logits ----------------------------------
__global__ __launch_bounds__(256) void k_final(const ushort* __restrict__ seqs,
                                               const float* __restrict__ sc,
                                               const float* __restrict__ bi,
                                               const int* __restrict__ pos_seqs,
                                               const int* __restrict__ neg_seqs,
                                               const float* __restrict__ item_emb,
                                               float* __restrict__ out) {
  int tok = blockIdx.x * 4 + (threadIdx.x >> 6);
  int lane = threadIdx.x & 63;
  ushort4 xu = ((const ushort4*)(seqs + (size_t)tok * D))[lane];
  float x0 = bf2f(xu.x), x1 = bf2f(xu.y), x2 = bf2f(xu.z), x3 = bf2f(xu.w);
  float mean = wave_sum(x0 + x1 + x2 + x3) * (1.0f / D);
  float c0 = x0 - mean, c1 = x1 - mean, c2 = x2 - mean, c3 = x3 - mean;
  float var = wave_sum(c0 * c0 + c1 * c1 + c2 * c2 + c3 * c3) * (1.0f / D);
  float inv = rsqrtf(var + 1e-8f);
  float4 sv = ((const float4*)sc)[lane];
  float4 bv = ((const float4*)bi)[lane];
  float f0 = c0 * inv * sv.x + bv.x;
  float f1 = c1 * inv * sv.y + bv.y;
  float f2 = c2 * inv * sv.z + bv.z;
  float f3 = c3 * inv * sv.w + bv.w;
  int ip = pos_seqs[tok];
  int in_ = neg_seqs[tok];
  float4 pe = ((const float4*)(item_emb + (size_t)ip * D))[lane];
  float4 ne = ((const float4*)(item_emb + (size_t)in_ * D))[lane];
  float dp = wave_sum(f0 * pe.x + f1 * pe.y + f2 * pe.z + f3 * pe.w);
  float dn = wave_sum(f0 * ne.x + f1 * ne.y + f2 * ne.z + f3 * ne.w);
  if (lane == 0) {
    out[tok] = dp;
    out[BT + tok] = dn;
  }
}

}  // namespace

extern "C" void kernel_launch(void* const* d_in, const int* in_sizes, int n_in,
                              void* d_out, int out_size, void* d_ws, size_t ws_size,
                              hipStream_t stream) {
  const int*   log_seqs   = (const int*)d_in[0];
  const int*   pos_seqs   = (const int*)d_in[1];
  const int*   neg_seqs   = (const int*)d_in[2];
  const int*   expert_ids = (const int*)d_in[3];
  const float* item_emb   = (const float*)d_in[4];
  const float* pos_emb    = (const float*)d_in[5];
  const float* attn_ln_s  = (const float*)d_in[6];
  const float* attn_ln_b  = (const float*)d_in[7];
  const float* in_w       = (const float*)d_in[8];
  const float* in_b       = (const float*)d_in[9];
  const float* out_w      = (const float*)d_in[10];
  const float* out_b      = (const float*)d_in[11];
  const float* fwd_ln_s   = (const float*)d_in[12];
  const float* fwd_ln_b   = (const float*)d_in[13];
  const float* ffn_w1     = (const float*)d_in[14];
  const float* ffn_b1     = (const float*)d_in[15];
  const float* ffn_w2     = (const float*)d_in[16];
  const float* ffn_b2     = (const float*)d_in[17];
  const float* last_ln_s  = (const float*)d_in[18];
  const float* last_ln_b  = (const float*)d_in[19];
  float* out = (float*)d_out;

  const size_t N = (size_t)BT * D;
  ushort* seqs = (ushort*)d_ws;
  ushort* qn   = seqs + N;
  ushort* q    = qn + N;
  ushort* kbuf = q + N;
  ushort* vbuf = kbuf + N;
  ushort* obuf = kbuf;   // alias: attn stages K to LDS before writing o
  ushort* wqkv = vbuf + N;                               // [NL][NE][3D][D]
  ushort* wout = wqkv + (size_t)NL * NE * 3 * D * D;     // [NL][NE][D][D]
  ushort* wf1  = wout + (size_t)NL * NE * D * D;         // [NL][D][D]
  ushort* wf2  = wf1 + (size_t)NL * D * D;               // [NL][D][D]

  {
    int n4a = NL * NE * 3 * D * D / 4;
    int n4b = NL * NE * D * D / 4;
    int n4c = NL * D * D / 4;
    k_cvt<<<(n4a + 255) / 256, 256, 0, stream>>>(in_w, wqkv, n4a);
    k_cvt<<<(n4b + 255) / 256, 256, 0, stream>>>(out_w, wout, n4b);
    k_cvt<<<(n4c + 255) / 256, 256, 0, stream>>>(ffn_w1, wf1, n4c);
    k_cvt<<<(n4c + 255) / 256, 256, 0, stream>>>(ffn_w2, wf2, n4c);
  }

  k_embed_ln<<<BT / 4, 256, 0, stream>>>(log_seqs, item_emb, pos_emb,
                                         attn_ln_s, attn_ln_b, seqs, qn);

  for (int l = 0; l < NL; l++) {
    int ln_next = (l + 1 < NL) ? (l + 1) : l;   // last-layer qn write unused
    k_gemm_qkv<<<B * MT * 6, 256, 0, stream>>>(
        qn, seqs, wqkv + (size_t)l * NE * 3 * D * D,
        in_b + (size_t)l * NE * 3 * D, expert_ids, q, kbuf, vbuf);
    k_attn<<<B * H, 256, 0, stream>>>(q, kbuf, vbuf, obuf);
    k_oproj<<<B * MT, 256, 0, stream>>>(
        obuf, qn, wout + (size_t)l * NE * D * D, out_b + (size_t)l * NE * D,
        fwd_ln_s + (size_t)l * D, fwd_ln_b + (size_t)l * D, expert_ids, seqs);
    k_ffn<<<B * MT, 256, 0, stream>>>(
        seqs, wf1 + (size_t)l * D * D, ffn_b1 + (size_t)l * D,
        wf2 + (size_t)l * D * D, ffn_b2 + (size_t)l * D,
        attn_ln_s + (size_t)ln_next * D, attn_ln_b + (size_t)ln_next * D,
        seqs, qn);
  }

  k_final<<<BT / 4, 256, 0, stream>>>(seqs, last_ln_s, last_ln_b, pos_seqs,
                                      neg_seqs, item_emb, out);
}